// Round 12
// baseline (201.769 us; speedup 1.0000x reference)
//
#include <hip/hip_runtime.h>
#include <hip/hip_bf16.h>
#include <cstdint>
#include <cstddef>

#define SEQ 2048
#define NBATCH 4
#define EMB 1024
#define NH 16
#define HD 64
#define MTOT (NBATCH * SEQ)   // 8192

typedef __attribute__((ext_vector_type(8))) short bf16x8;
typedef __attribute__((ext_vector_type(4))) float f32x4;
typedef __attribute__((ext_vector_type(16))) float f32x16;
typedef unsigned short u16;
typedef unsigned int u32;

__device__ __forceinline__ float bf2f(u16 v) {
  union { u32 u; float f; } c; c.u = ((u32)v) << 16; return c.f;
}
__device__ __forceinline__ u16 f2bf(float f) {
  union { float f; u32 u; } c; c.f = f;
  u32 u = c.u;
  return (u16)((u + 0x7FFFu + ((u >> 16) & 1u)) >> 16);
}
__device__ __forceinline__ u32 f2u(float f) {
  union { float f; u32 u; } c; c.f = f; return c.u;
}

// ---------------- fused prep: casts (x, W_qkv, W_out) + RoPE table ----------------
__global__ void prep_kernel(const float* __restrict__ x, const float* __restrict__ wqkv,
                            const float* __restrict__ wout,
                            u16* __restrict__ xb, u16* __restrict__ wqkvb,
                            u16* __restrict__ woutb, float* __restrict__ tab2) {
  int tid = blockIdx.x * blockDim.x + threadIdx.x;
  int stride = gridDim.x * blockDim.x;
  for (int i = tid; i < MTOT * EMB / 4; i += stride) {
    float4 v = reinterpret_cast<const float4*>(x)[i];
    ushort4 o;
    o.x = f2bf(v.x); o.y = f2bf(v.y); o.z = f2bf(v.z); o.w = f2bf(v.w);
    reinterpret_cast<ushort4*>(xb)[i] = o;
  }
  for (int i = tid; i < 3 * EMB * EMB / 4; i += stride) {
    float4 v = reinterpret_cast<const float4*>(wqkv)[i];
    ushort4 o;
    o.x = f2bf(v.x); o.y = f2bf(v.y); o.z = f2bf(v.z); o.w = f2bf(v.w);
    reinterpret_cast<ushort4*>(wqkvb)[i] = o;
  }
  for (int i = tid; i < EMB * EMB / 4; i += stride) {
    float4 v = reinterpret_cast<const float4*>(wout)[i];
    ushort4 o;
    o.x = f2bf(v.x); o.y = f2bf(v.y); o.z = f2bf(v.z); o.w = f2bf(v.w);
    reinterpret_cast<ushort4*>(woutb)[i] = o;
  }
  for (int i = tid; i < SEQ * 32; i += stride) {
    int n = i >> 5, j = i & 31;
    float invf = 1.0f / powf(10000.0f, (float)(2 * j) / 64.0f);
    float ang = (float)n * invf;
    tab2[2 * i] = cosf(ang);
    tab2[2 * i + 1] = sinf(ang);
  }
}

// ---------------- async global->LDS helper (16B) ----------------
__device__ __forceinline__ void gld_lds16(const u16* g, u16* l) {
  __builtin_amdgcn_global_load_lds((const __attribute__((address_space(1))) void*)g,
                                   (__attribute__((address_space(3))) void*)l, 16, 0, 0);
}

// ---------------- GEMM: C[M,N] = A[M,K] * Bw[N,K]^T + bias (out-proj, fp32 out) ----------------
__global__ __launch_bounds__(256, 2)
void gemm_bt_f32(const u16* __restrict__ A, const u16* __restrict__ Bw,
                 const float* __restrict__ bias, float* __restrict__ Cout,
                 int N, int tiles_n) {
  __shared__ u16 lA[128 * 64];
  __shared__ u16 lB[128 * 64];
  const int K = 1024;
  int bm = blockIdx.x / tiles_n;
  int bn = blockIdx.x % tiles_n;
  int t = threadIdx.x;
  int wave = t >> 6, lane = t & 63;
  int wm = wave >> 1, wn = wave & 1;
  int l15 = lane & 15, l4 = lane >> 4;

  f32x4 acc[4][4];
#pragma unroll
  for (int i = 0; i < 4; ++i)
#pragma unroll
    for (int j = 0; j < 4; ++j) acc[i][j] = (f32x4){0.f, 0.f, 0.f, 0.f};

  int su[4], sr[4], sc[4];
#pragma unroll
  for (int i = 0; i < 4; ++i) {
    int u = (i * 4 + wave) * 64 + lane;
    su[i] = u;
    sr[i] = u >> 3;
    sc[i] = (u & 7) ^ (sr[i] & 7);
  }

  for (int kt = 0; kt < K / 64; ++kt) {
    if (kt) __syncthreads();
#pragma unroll
    for (int i = 0; i < 4; ++i) {
      gld_lds16(A + (size_t)(bm * 128 + sr[i]) * K + kt * 64 + sc[i] * 8, &lA[su[i] * 8]);
      gld_lds16(Bw + (size_t)(bn * 128 + sr[i]) * K + kt * 64 + sc[i] * 8, &lB[su[i] * 8]);
    }
    __syncthreads();
#pragma unroll
    for (int ks = 0; ks < 2; ++ks) {
      bf16x8 af[4], bfr[4];
#pragma unroll
      for (int mb = 0; mb < 4; ++mb) {
        int r = wm * 64 + mb * 16 + l15;
        int cc = (ks * 4 + l4) ^ (r & 7);
        af[mb] = *reinterpret_cast<const bf16x8*>(&lA[r * 64 + cc * 8]);
      }
#pragma unroll
      for (int nb = 0; nb < 4; ++nb) {
        int r = wn * 64 + nb * 16 + l15;
        int cc = (ks * 4 + l4) ^ (r & 7);
        bfr[nb] = *reinterpret_cast<const bf16x8*>(&lB[r * 64 + cc * 8]);
      }
#pragma unroll
      for (int mb = 0; mb < 4; ++mb)
#pragma unroll
        for (int nb = 0; nb < 4; ++nb)
          acc[mb][nb] = __builtin_amdgcn_mfma_f32_16x16x32_bf16(af[mb], bfr[nb], acc[mb][nb], 0, 0, 0);
    }
  }

#pragma unroll
  for (int mb = 0; mb < 4; ++mb)
#pragma unroll
    for (int nb = 0; nb < 4; ++nb) {
      int row0 = bm * 128 + wm * 64 + mb * 16 + l4 * 4;
      int col = bn * 128 + wn * 64 + nb * 16 + l15;
      float bv = bias[col];
#pragma unroll
      for (int r = 0; r < 4; ++r)
        Cout[(size_t)(row0 + r) * N + col] = acc[mb][nb][r] + bv;
    }
}

// ---------------- fused QKV GEMM v2: 256x128 tile, 8 waves, 3-buffer counted-vmcnt pipeline ----------------
// 512 threads = 8 waves (4m x 2n); wave tile 64x64 (1 head). Tile T+2 staged into buf[(T+2)%3]
// during tile T (that buffer's last reader = tile T-1, barrier-separated -> race-free).
// End-of-tile vmcnt(6) guarantees tile T+1 landed; the loop NEVER drains vmcnt to 0 (T4).
// Raw s_barrier (not __syncthreads) avoids the implicit vmcnt(0) full drain.
// B rows tau-permuted within 64-row blocks -> RoPE pairs in-thread + coalesced u32 stores.
__global__ __launch_bounds__(512, 2)
void gemm_qkv_rope(const u16* __restrict__ A, const u16* __restrict__ Bw,
                   const float* __restrict__ bias, const float* __restrict__ tab2,
                   u16* __restrict__ Qb, u16* __restrict__ Kb, u16* __restrict__ Vtb) {
  __shared__ u16 lA[3][256 * 64];   // 96 KB
  __shared__ u16 lB[3][128 * 64];   // 48 KB
  const int K = 1024;
  int bid = blockIdx.x;
  int swz = (bid & 7) * 96 + (bid >> 3);   // 768 % 8 == 0 -> bijective XCD chunking
  int bm = swz / 24;
  int bn = swz % 24;
  int t = threadIdx.x;
  int wave = t >> 6, lane = t & 63;
  int wm = wave >> 1, wn = wave & 1;
  int l15 = lane & 15, l4 = lane >> 4;

  f32x4 acc[4][4];
#pragma unroll
  for (int i = 0; i < 4; ++i)
#pragma unroll
    for (int j = 0; j < 4; ++j) acc[i][j] = (f32x4){0.f, 0.f, 0.f, 0.f};

  // per-thread staging offsets: A 4 units (2048 units / 512 thr), B 2 units (tau-permuted rows)
  size_t aoff[4]; int aldst[4];
#pragma unroll
  for (int j = 0; j < 4; ++j) {
    int u = j * 512 + t;
    int r = u >> 3, c = u & 7;
    int sc = c ^ (r & 7);                 // inverse chunk swizzle on global source
    aoff[j] = (size_t)(bm * 256 + r) * K + sc * 8;
    aldst[j] = u * 8;
  }
  size_t boff[2]; int bldst[2];
#pragma unroll
  for (int j = 0; j < 2; ++j) {
    int u = j * 512 + t;
    int r = u >> 3, c = u & 7;
    int sc = c ^ (r & 7);
    int rr = r & 63;
    int tr = (r & 64) | (rr & 32) | ((rr & 15) << 1) | ((rr >> 4) & 1);  // tau perm
    boff[j] = (size_t)(bn * 128 + tr) * K + sc * 8;
    bldst[j] = u * 8;
  }
  auto stage = [&](int buf, int kt) {
    gld_lds16(Bw + boff[0] + kt * 64, &lB[buf][bldst[0]]);
    gld_lds16(Bw + boff[1] + kt * 64, &lB[buf][bldst[1]]);
    gld_lds16(A + aoff[0] + kt * 64, &lA[buf][aldst[0]]);
    gld_lds16(A + aoff[1] + kt * 64, &lA[buf][aldst[1]]);
    gld_lds16(A + aoff[2] + kt * 64, &lA[buf][aldst[2]]);
    gld_lds16(A + aoff[3] + kt * 64, &lA[buf][aldst[3]]);
  };

  stage(0, 0);
  stage(1, 1);
  asm volatile("s_waitcnt vmcnt(6)" ::: "memory");   // tile 0 landed (tile 1 in flight)
  __builtin_amdgcn_s_barrier();

  int cbuf = 0;
  for (int kt = 0; kt < 16; ++kt) {
    // B fragments for this wave's head (read once per K-tile)
    bf16x8 bfr[4][2];
#pragma unroll
    for (int nb = 0; nb < 4; ++nb)
#pragma unroll
      for (int kh = 0; kh < 2; ++kh) {
        int r = wn * 64 + nb * 16 + l15;
        int cc = (kh * 4 + l4) ^ (r & 7);
        bfr[nb][kh] = *reinterpret_cast<const bf16x8*>(&lB[cbuf][r * 64 + cc * 8]);
      }
    int nbuf = cbuf + 2; if (nbuf >= 3) nbuf -= 3;
    if (kt + 2 < 16) stage(nbuf, kt + 2);   // issue-early (T14): waits 2 tiles later

#pragma unroll
    for (int mb = 0; mb < 4; ++mb) {
      bf16x8 af[2];
#pragma unroll
      for (int kh = 0; kh < 2; ++kh) {
        int r = wm * 64 + mb * 16 + l15;
        int cc = (kh * 4 + l4) ^ (r & 7);
        af[kh] = *reinterpret_cast<const bf16x8*>(&lA[cbuf][r * 64 + cc * 8]);
      }
      __builtin_amdgcn_s_setprio(1);
#pragma unroll
      for (int nb = 0; nb < 4; ++nb) {
        acc[mb][nb] = __builtin_amdgcn_mfma_f32_16x16x32_bf16(af[0], bfr[nb][0], acc[mb][nb], 0, 0, 0);
        acc[mb][nb] = __builtin_amdgcn_mfma_f32_16x16x32_bf16(af[1], bfr[nb][1], acc[mb][nb], 0, 0, 0);
      }
      __builtin_amdgcn_s_setprio(0);
    }

    if (kt < 14)       asm volatile("s_waitcnt vmcnt(6)" ::: "memory");  // tile kt+1 landed
    else if (kt == 14) asm volatile("s_waitcnt vmcnt(0)" ::: "memory");  // tile 15 landed
    if (kt < 15) __builtin_amdgcn_s_barrier();
    cbuf = cbuf + 1; if (cbuf >= 3) cbuf -= 3;
  }

  // ---- fused epilogue (identical math to 128-col version; row base bm*256) ----
  int type = bn >> 3;            // 0=q, 1=k, 2=v
  int h = (bn * 2 + wn) & 15;    // head
  int colbase = bn * 128 + wn * 64;
  float bv[4];
#pragma unroll
  for (int nb = 0; nb < 4; ++nb)
    bv[nb] = bias[colbase + 32 * (nb >> 1) + 2 * l15 + (nb & 1)];

  if (type < 2) {
    u16* dst0 = (type == 0) ? Qb : Kb;
    float qs = (type == 0) ? 0.1803368801111163f : 1.0f;  // (1/8)*log2(e) folded into q
#pragma unroll
    for (int mb = 0; mb < 4; ++mb) {
      int row0 = bm * 256 + wm * 64 + mb * 16 + l4 * 4;
#pragma unroll
      for (int r = 0; r < 4; ++r) {
        int row = row0 + r;
        int bb = row >> 11, nl = row & 2047;
        float4 cs4 = *reinterpret_cast<const float4*>(tab2 + (size_t)nl * 64 + 4 * l15);
        float a0 = acc[mb][0][r] + bv[0];   // d = 2l15
        float a1 = acc[mb][1][r] + bv[1];   // d = 2l15+1
        float a2 = acc[mb][2][r] + bv[2];   // d = 2l15+32
        float a3 = acc[mb][3][r] + bv[3];   // d = 2l15+33
        float o0 = (a0 * cs4.x - a2 * cs4.y) * qs;
        float o2 = (a2 * cs4.x + a0 * cs4.y) * qs;
        float o1 = (a1 * cs4.z - a3 * cs4.w) * qs;
        float o3 = (a3 * cs4.z + a1 * cs4.w) * qs;
        u16* dst = dst0 + ((size_t)(bb * 16 + h) * SEQ + nl) * 64;
        u32 lo = (u32)f2bf(o0) | ((u32)f2bf(o1) << 16);
        u32 hi2 = (u32)f2bf(o2) | ((u32)f2bf(o3) << 16);
        *reinterpret_cast<u32*>(&dst[2 * l15]) = lo;
        *reinterpret_cast<u32*>(&dst[32 + 2 * l15]) = hi2;
      }
    }
  } else {
#pragma unroll
    for (int mb = 0; mb < 4; ++mb) {
      int row0 = bm * 256 + wm * 64 + mb * 16 + l4 * 4;
      int bb = row0 >> 11, nl0 = row0 & 2047;
#pragma unroll
      for (int nb = 0; nb < 4; ++nb) {
        int d = 32 * (nb >> 1) + 2 * l15 + (nb & 1);
        ushort4 pk;
        pk.x = f2bf(acc[mb][nb][0] + bv[nb]);
        pk.y = f2bf(acc[mb][nb][1] + bv[nb]);
        pk.z = f2bf(acc[mb][nb][2] + bv[nb]);
        pk.w = f2bf(acc[mb][nb][3] + bv[nb]);
        *reinterpret_cast<ushort4*>(&Vtb[((size_t)(bb * 16 + h) * 64 + d) * SEQ + nl0]) = pk;
      }
    }
  }
}

// ---------------- attention v9 (round-9 verbatim): reg-staged padded chunk-major LDS ----------------
__global__ __launch_bounds__(256, 4)
void attn_kernel(const u16* __restrict__ Q, const u16* __restrict__ Kk,
                 const u16* __restrict__ Vt, u16* __restrict__ Out) {
  int bid = blockIdx.x;
  int swz = (bid & 7) * 128 + (bid >> 3);  // XCD-chunked: each XCD owns 8 heads (4MB = L2)
  int bh = swz >> 4;
  int qt = swz & 15;
  int b = bh >> 4, h = bh & 15;
  int t = threadIdx.x;
  int wave = t >> 6, lane = t & 63;
  int l31 = lane & 31, hi = lane >> 5;

  __shared__ u16 lK[2][520 * 8];  // 8 chunks * 65 (64 rows + 1 pad) 16B slots
  __shared__ u16 lV[2][520 * 8];

  const u16* Qh = Q + (size_t)bh * SEQ * 64;
  const u16* Kh = Kk + (size_t)bh * SEQ * 64;
  const u16* Vh = Vt + (size_t)bh * 64 * SEQ;
  int q0w = qt * 128 + wave * 32;

  bf16x8 qf[4];
#pragma unroll
  for (int dc = 0; dc < 4; ++dc)
    qf[dc] = *reinterpret_cast<const bf16x8*>(
        &Qh[(size_t)(q0w + l31) * 64 + dc * 16 + hi * 8]);

  f32x16 oacc[2];
#pragma unroll
  for (int db = 0; db < 2; ++db)
#pragma unroll
    for (int r = 0; r < 16; ++r) oacc[db][r] = 0.f;
  float dn = 0.f;

  bf16x8 kreg[2], vreg[2];
  auto stage_load = [&](int kt) {
#pragma unroll
    for (int p = 0; p < 2; ++p) {
      int u = p * 256 + t;
      int r = u >> 3, c = u & 7;
      kreg[p] = *reinterpret_cast<const bf16x8*>(&Kh[(size_t)(kt * 64 + r) * 64 + c * 8]);
      vreg[p] = *reinterpret_cast<const bf16x8*>(&Vh[(size_t)r * SEQ + kt * 64 + c * 8]);
    }
  };
  auto stage_write = [&](int buf) {
#pragma unroll
    for (int p = 0; p < 2; ++p) {
      int u = p * 256 + t;
      int r = u >> 3, c = u & 7;
      *reinterpret_cast<bf16x8*>(&lK[buf][(c * 65 + r) * 8]) = kreg[p];
      *reinterpret_cast<bf16x8*>(&lV[buf][(c * 65 + r) * 8]) = vreg[p];
    }
  };

  union PF { u32 w[4]; bf16x8 v; };
  int cur = 0;
  stage_load(0);
  stage_write(0);
  __syncthreads();
  for (int kt = 0; kt < SEQ / 64; ++kt) {
    if (kt + 1 < SEQ / 64) stage_load(kt + 1);  // in flight across compute (T14)

    f32x16 s[2];
#pragma unroll
    for (int cb = 0; cb < 2; ++cb)
#pragma unroll
      for (int r = 0; r < 16; ++r) s[cb][r] = 0.f;
    __builtin_amdgcn_s_setprio(1);
#pragma unroll
    for (int cb = 0; cb < 2; ++cb) {
#pragma unroll
      for (int dc = 0; dc < 4; ++dc) {
        bf16x8 kf = *reinterpret_cast<const bf16x8*>(
            &lK[cur][((dc * 2 + hi) * 65 + cb * 32 + l31) * 8]);
        s[cb] = __builtin_amdgcn_mfma_f32_32x32x16_bf16(kf, qf[dc], s[cb], 0, 0, 0);
      }
    }
    __builtin_amdgcn_s_setprio(0);

    PF pa[2][2];
#pragma unroll
    for (int cb = 0; cb < 2; ++cb) {
#pragma unroll
      for (int r = 0; r < 16; ++r) {
        float e = __builtin_amdgcn_exp2f(s[cb][r]);
        s[cb][r] = e;
        dn += e;
      }
#pragma unroll
      for (int c = 0; c < 2; ++c) {
        u32 u0 = f2u(s[cb][8 * c + 0]) + 0x8000u;
        u32 u1 = f2u(s[cb][8 * c + 1]) + 0x8000u;
        u32 u2 = f2u(s[cb][8 * c + 2]) + 0x8000u;
        u32 u3 = f2u(s[cb][8 * c + 3]) + 0x8000u;
        u32 u4 = f2u(s[cb][8 * c + 4]) + 0x8000u;
        u32 u5 = f2u(s[cb][8 * c + 5]) + 0x8000u;
        u32 u6 = f2u(s[cb][8 * c + 6]) + 0x8000u;
        u32 u7 = f2u(s[cb][8 * c + 7]) + 0x8000u;
        u32 a1 = __builtin_amdgcn_perm(u1, u0, 0x07060302);  // bf16(e1)<<16 | bf16(e0)
        u32 a2 = __builtin_amdgcn_perm(u3, u2, 0x07060302);
        u32 b1 = __builtin_amdgcn_perm(u5, u4, 0x07060302);
        u32 b2 = __builtin_amdgcn_perm(u7, u6, 0x07060302);
        asm("v_permlane32_swap_b32 %0, %1" : "+v"(a1), "+v"(b1));
        asm("v_permlane32_swap_b32 %0, %1" : "+v"(a2), "+v"(b2));
        pa[cb][c].w[0] = a1; pa[cb][c].w[1] = a2;
        pa[cb][c].w[2] = b1; pa[cb][c].w[3] = b2;
      }
    }

    __builtin_amdgcn_s_setprio(1);
#pragma unroll
    for (int cb = 0; cb < 2; ++cb)
#pragma unroll
      for (int c = 0; c < 2; ++c)
#pragma unroll
        for (int db = 0; db < 2; ++db) {
          bf16x8 vf = *reinterpret_cast<const bf16x8*>(
              &lV[cur][((cb * 4 + c * 2 + hi) * 65 + db * 32 + l31) * 8]);
          oacc[db] = __builtin_amdgcn_mfma_f32_32x32x16_bf16(pa[cb][c].v, vf, oacc[db], 0, 0, 0);
        }
    __builtin_amdgcn_s_setprio(0);

    if (kt + 1 < SEQ / 64) stage_write(cur ^ 1);  // implicit vmcnt wait lands here
    __syncthreads();
    cur ^= 1;
  }

  dn += __shfl_xor(dn, 32);
#pragma unroll
  for (int r = 0; r < 16; ++r) {
    int qrel = (r & 3) + 8 * (r >> 2) + 4 * hi;
    float dfull = __shfl(dn, qrel);
    float inv = __builtin_amdgcn_rcpf(dfull);
    int q = q0w + qrel;
#pragma unroll
    for (int db = 0; db < 2; ++db) {
      int d = db * 32 + l31;
      Out[(size_t)(b * SEQ + q) * EMB + h * 64 + d] = f2bf(oacc[db][r] * inv);
    }
  }
}

// ---------------- launch ----------------
extern "C" void kernel_launch(void* const* d_in, const int* in_sizes, int n_in,
                              void* d_out, int out_size, void* d_ws, size_t ws_size,
                              hipStream_t stream) {
  const float* x = (const float*)d_in[0];
  const float* bqkv = (const float*)d_in[2];
  const float* bout = (const float*)d_in[4];
  float* out = (float*)d_out;

  char* ws = (char*)d_ws;
  size_t off = 0;
  auto alloc = [&](size_t bytes) {
    void* p = ws + off;
    off += (bytes + 255) & ~(size_t)255;
    return p;
  };
  u16* xb    = (u16*)alloc((size_t)MTOT * EMB * 2);
  u16* wqkvb = (u16*)alloc((size_t)3 * EMB * EMB * 2);
  u16* woutb = (u16*)alloc((size_t)EMB * EMB * 2);
  u16* Qb    = (u16*)alloc((size_t)64 * SEQ * HD * 2);
  u16* Kb    = (u16*)alloc((size_t)64 * SEQ * HD * 2);
  u16* Vtb   = (u16*)alloc((size_t)64 * HD * SEQ * 2);
  u16* aout  = (u16*)alloc((size_t)MTOT * EMB * 2);
  float* tab2 = (float*)alloc((size_t)SEQ * 32 * 2 * 4);
  (void)ws_size; (void)in_sizes; (void)n_in; (void)out_size;

  prep_kernel<<<2048, 256, 0, stream>>>(x, (const float*)d_in[1], (const float*)d_in[3],
                                        xb, wqkvb, woutb, tab2);
  gemm_qkv_rope<<<768, 512, 0, stream>>>(xb, wqkvb, bqkv, tab2, Qb, Kb, Vtb);
  attn_kernel<<<64 * 16, 256, 0, stream>>>(Qb, Kb, Vtb, aout);
  gemm_bt_f32<<<64 * 8, 256, 0, stream>>>(aout, woutb, bout, out, EMB, 8);
}

// Round 13
// 176.192 us; speedup vs baseline: 1.1452x; 1.1452x over previous
//
#include <hip/hip_runtime.h>
#include <hip/hip_bf16.h>
#include <cstdint>
#include <cstddef>

#define SEQ 2048
#define NBATCH 4
#define EMB 1024
#define NH 16
#define HD 64
#define MTOT (NBATCH * SEQ)   // 8192

typedef __attribute__((ext_vector_type(8))) short bf16x8;
typedef __attribute__((ext_vector_type(4))) float f32x4;
typedef __attribute__((ext_vector_type(16))) float f32x16;
typedef unsigned short u16;
typedef unsigned int u32;

__device__ __forceinline__ float bf2f(u16 v) {
  union { u32 u; float f; } c; c.u = ((u32)v) << 16; return c.f;
}
__device__ __forceinline__ u16 f2bf(float f) {
  union { float f; u32 u; } c; c.f = f;
  u32 u = c.u;
  return (u16)((u + 0x7FFFu + ((u >> 16) & 1u)) >> 16);
}
__device__ __forceinline__ u32 f2u(float f) {
  union { float f; u32 u; } c; c.f = f; return c.u;
}

// ---------------- fused prep: casts (x, W_qkv, W_out) + RoPE table ----------------
__global__ void prep_kernel(const float* __restrict__ x, const float* __restrict__ wqkv,
                            const float* __restrict__ wout,
                            u16* __restrict__ xb, u16* __restrict__ wqkvb,
                            u16* __restrict__ woutb, float* __restrict__ tab2) {
  int tid = blockIdx.x * blockDim.x + threadIdx.x;
  int stride = gridDim.x * blockDim.x;
  for (int i = tid; i < MTOT * EMB / 4; i += stride) {
    float4 v = reinterpret_cast<const float4*>(x)[i];
    ushort4 o;
    o.x = f2bf(v.x); o.y = f2bf(v.y); o.z = f2bf(v.z); o.w = f2bf(v.w);
    reinterpret_cast<ushort4*>(xb)[i] = o;
  }
  for (int i = tid; i < 3 * EMB * EMB / 4; i += stride) {
    float4 v = reinterpret_cast<const float4*>(wqkv)[i];
    ushort4 o;
    o.x = f2bf(v.x); o.y = f2bf(v.y); o.z = f2bf(v.z); o.w = f2bf(v.w);
    reinterpret_cast<ushort4*>(wqkvb)[i] = o;
  }
  for (int i = tid; i < EMB * EMB / 4; i += stride) {
    float4 v = reinterpret_cast<const float4*>(wout)[i];
    ushort4 o;
    o.x = f2bf(v.x); o.y = f2bf(v.y); o.z = f2bf(v.z); o.w = f2bf(v.w);
    reinterpret_cast<ushort4*>(woutb)[i] = o;
  }
  for (int i = tid; i < SEQ * 32; i += stride) {
    int n = i >> 5, j = i & 31;
    float invf = 1.0f / powf(10000.0f, (float)(2 * j) / 64.0f);
    float ang = (float)n * invf;
    tab2[2 * i] = cosf(ang);
    tab2[2 * i + 1] = sinf(ang);
  }
}

// ---------------- async global->LDS helper (16B) ----------------
__device__ __forceinline__ void gld_lds16(const u16* g, u16* l) {
  __builtin_amdgcn_global_load_lds((const __attribute__((address_space(1))) void*)g,
                                   (__attribute__((address_space(3))) void*)l, 16, 0, 0);
}

// ---------------- GEMM: C[M,N] = A[M,K] * Bw[N,K]^T + bias (out-proj, fp32 out) ----------------
// XCD-locality swizzle: bm%8 == XCD -> each A row-tile is fetched by exactly one XCD's L2.
__global__ __launch_bounds__(256, 2)
void gemm_bt_f32(const u16* __restrict__ A, const u16* __restrict__ Bw,
                 const float* __restrict__ bias, float* __restrict__ Cout,
                 int N, int tiles_n) {
  __shared__ u16 lA[128 * 64];
  __shared__ u16 lB[128 * 64];
  const int K = 1024;
  int g = blockIdx.x;
  int xcd = g & 7, idx = g >> 3;
  int bm = (idx & 7) * 8 + xcd;     // bm%8 == xcd (64 bm values per 8 XCDs)
  int bn = idx >> 3;                // 0..tiles_n-1
  int t = threadIdx.x;
  int wave = t >> 6, lane = t & 63;
  int wm = wave >> 1, wn = wave & 1;
  int l15 = lane & 15, l4 = lane >> 4;

  f32x4 acc[4][4];
#pragma unroll
  for (int i = 0; i < 4; ++i)
#pragma unroll
    for (int j = 0; j < 4; ++j) acc[i][j] = (f32x4){0.f, 0.f, 0.f, 0.f};

  int su[4], sr[4], sc[4];
#pragma unroll
  for (int i = 0; i < 4; ++i) {
    int u = (i * 4 + wave) * 64 + lane;
    su[i] = u;
    sr[i] = u >> 3;
    sc[i] = (u & 7) ^ (sr[i] & 7);
  }

  for (int kt = 0; kt < K / 64; ++kt) {
    if (kt) __syncthreads();
#pragma unroll
    for (int i = 0; i < 4; ++i) {
      gld_lds16(A + (size_t)(bm * 128 + sr[i]) * K + kt * 64 + sc[i] * 8, &lA[su[i] * 8]);
      gld_lds16(Bw + (size_t)(bn * 128 + sr[i]) * K + kt * 64 + sc[i] * 8, &lB[su[i] * 8]);
    }
    __syncthreads();
#pragma unroll
    for (int ks = 0; ks < 2; ++ks) {
      bf16x8 af[4], bfr[4];
#pragma unroll
      for (int mb = 0; mb < 4; ++mb) {
        int r = wm * 64 + mb * 16 + l15;
        int cc = (ks * 4 + l4) ^ (r & 7);
        af[mb] = *reinterpret_cast<const bf16x8*>(&lA[r * 64 + cc * 8]);
      }
#pragma unroll
      for (int nb = 0; nb < 4; ++nb) {
        int r = wn * 64 + nb * 16 + l15;
        int cc = (ks * 4 + l4) ^ (r & 7);
        bfr[nb] = *reinterpret_cast<const bf16x8*>(&lB[r * 64 + cc * 8]);
      }
#pragma unroll
      for (int mb = 0; mb < 4; ++mb)
#pragma unroll
        for (int nb = 0; nb < 4; ++nb)
          acc[mb][nb] = __builtin_amdgcn_mfma_f32_16x16x32_bf16(af[mb], bfr[nb], acc[mb][nb], 0, 0, 0);
    }
  }

#pragma unroll
  for (int mb = 0; mb < 4; ++mb)
#pragma unroll
    for (int nb = 0; nb < 4; ++nb) {
      int row0 = bm * 128 + wm * 64 + mb * 16 + l4 * 4;
      int col = bn * 128 + wn * 64 + nb * 16 + l15;
      float bv = bias[col];
#pragma unroll
      for (int r = 0; r < 4; ++r)
        Cout[(size_t)(row0 + r) * N + col] = acc[mb][nb][r] + bv;
    }
}

// ---------------- fused QKV GEMM + bias + RoPE + scatter (coalesced Q/K stores) ----------------
// B-tile rows permuted within each 64-row half: LDS row (nb,l15) holds weight col
// d = 32*(nb>>1) + 2*l15 + (nb&1), so each thread owns head-dims {2l15, 2l15+1, +32, +33}:
// RoPE pairs in-thread AND Q/K stores become two u32 (4B) stores -> 64B runs across lanes.
// XCD-locality swizzle: bm%8 == XCD (grid 1536 = 8 x 192, bijective).
__global__ __launch_bounds__(256, 2)
void gemm_qkv_rope(const u16* __restrict__ A, const u16* __restrict__ Bw,
                   const float* __restrict__ bias, const float* __restrict__ tab2,
                   u16* __restrict__ Qb, u16* __restrict__ Kb, u16* __restrict__ Vtb) {
  __shared__ u16 lA[128 * 64];
  __shared__ u16 lB[128 * 64];
  const int K = 1024;
  int g = blockIdx.x;
  int xcd = g & 7, idx = g >> 3;
  int bm = (idx & 7) * 8 + xcd;     // 0..63 ; bm%8 == xcd
  int bn = idx >> 3;                // 0..23
  int t = threadIdx.x;
  int wave = t >> 6, lane = t & 63;
  int wm = wave >> 1, wn = wave & 1;
  int l15 = lane & 15, l4 = lane >> 4;

  f32x4 acc[4][4];
#pragma unroll
  for (int i = 0; i < 4; ++i)
#pragma unroll
    for (int j = 0; j < 4; ++j) acc[i][j] = (f32x4){0.f, 0.f, 0.f, 0.f};

  int su[4], sr[4], sc[4];
#pragma unroll
  for (int i = 0; i < 4; ++i) {
    int u = (i * 4 + wave) * 64 + lane;
    su[i] = u;
    sr[i] = u >> 3;
    sc[i] = (u & 7) ^ (sr[i] & 7);
  }
  // B row permutation: within each 64-row half, LDS row rr holds weight row tau(rr)
  int tauB[4];
#pragma unroll
  for (int i = 0; i < 4; ++i) {
    int rr = sr[i] & 63;
    tauB[i] = (sr[i] & 64) | (rr & 32) | ((rr & 15) << 1) | ((rr >> 4) & 1);
  }

  for (int kt = 0; kt < K / 64; ++kt) {
    if (kt) __syncthreads();
#pragma unroll
    for (int i = 0; i < 4; ++i) {
      gld_lds16(A + (size_t)(bm * 128 + sr[i]) * K + kt * 64 + sc[i] * 8, &lA[su[i] * 8]);
      gld_lds16(Bw + (size_t)(bn * 128 + tauB[i]) * K + kt * 64 + sc[i] * 8, &lB[su[i] * 8]);
    }
    __syncthreads();
#pragma unroll
    for (int ks = 0; ks < 2; ++ks) {
      bf16x8 af[4], bfr[4];
#pragma unroll
      for (int mb = 0; mb < 4; ++mb) {
        int r = wm * 64 + mb * 16 + l15;
        int cc = (ks * 4 + l4) ^ (r & 7);
        af[mb] = *reinterpret_cast<const bf16x8*>(&lA[r * 64 + cc * 8]);
      }
#pragma unroll
      for (int nb = 0; nb < 4; ++nb) {
        int r = wn * 64 + nb * 16 + l15;
        int cc = (ks * 4 + l4) ^ (r & 7);
        bfr[nb] = *reinterpret_cast<const bf16x8*>(&lB[r * 64 + cc * 8]);
      }
#pragma unroll
      for (int mb = 0; mb < 4; ++mb)
#pragma unroll
        for (int nb = 0; nb < 4; ++nb)
          acc[mb][nb] = __builtin_amdgcn_mfma_f32_16x16x32_bf16(af[mb], bfr[nb], acc[mb][nb], 0, 0, 0);
    }
  }

  // ---- fused epilogue ----
  int type = bn >> 3;            // 0=q, 1=k, 2=v
  int h = (bn * 2 + wn) & 15;    // head
  int colbase = bn * 128 + wn * 64;
  // logical head-dim for (nb,l15): d = 32*(nb>>1) + 2*l15 + (nb&1)
  float bv[4];
#pragma unroll
  for (int nb = 0; nb < 4; ++nb)
    bv[nb] = bias[colbase + 32 * (nb >> 1) + 2 * l15 + (nb & 1)];

  if (type < 2) {
    u16* dst0 = (type == 0) ? Qb : Kb;
    float qs = (type == 0) ? 0.1803368801111163f : 1.0f;  // (1/8)*log2(e) folded into q
#pragma unroll
    for (int mb = 0; mb < 4; ++mb) {
      int row0 = bm * 128 + wm * 64 + mb * 16 + l4 * 4;
#pragma unroll
      for (int r = 0; r < 4; ++r) {
        int row = row0 + r;
        int bb = row >> 11, nl = row & 2047;
        float4 cs4 = *reinterpret_cast<const float4*>(tab2 + (size_t)nl * 64 + 4 * l15);
        float a0 = acc[mb][0][r] + bv[0];   // d = 2l15
        float a1 = acc[mb][1][r] + bv[1];   // d = 2l15+1
        float a2 = acc[mb][2][r] + bv[2];   // d = 2l15+32
        float a3 = acc[mb][3][r] + bv[3];   // d = 2l15+33
        float o0 = (a0 * cs4.x - a2 * cs4.y) * qs;
        float o2 = (a2 * cs4.x + a0 * cs4.y) * qs;
        float o1 = (a1 * cs4.z - a3 * cs4.w) * qs;
        float o3 = (a3 * cs4.z + a1 * cs4.w) * qs;
        u16* dst = dst0 + ((size_t)(bb * 16 + h) * SEQ + nl) * 64;
        u32 lo = (u32)f2bf(o0) | ((u32)f2bf(o1) << 16);
        u32 hi2 = (u32)f2bf(o2) | ((u32)f2bf(o3) << 16);
        *reinterpret_cast<u32*>(&dst[2 * l15]) = lo;
        *reinterpret_cast<u32*>(&dst[32 + 2 * l15]) = hi2;
      }
    }
  } else {
#pragma unroll
    for (int mb = 0; mb < 4; ++mb) {
      int row0 = bm * 128 + wm * 64 + mb * 16 + l4 * 4;
      int bb = row0 >> 11, nl0 = row0 & 2047;
#pragma unroll
      for (int nb = 0; nb < 4; ++nb) {
        int d = 32 * (nb >> 1) + 2 * l15 + (nb & 1);
        ushort4 pk;
        pk.x = f2bf(acc[mb][nb][0] + bv[nb]);
        pk.y = f2bf(acc[mb][nb][1] + bv[nb]);
        pk.z = f2bf(acc[mb][nb][2] + bv[nb]);
        pk.w = f2bf(acc[mb][nb][3] + bv[nb]);
        *reinterpret_cast<ushort4*>(&Vtb[((size_t)(bb * 16 + h) * 64 + d) * SEQ + nl0]) = pk;
      }
    }
  }
}

// ---------------- attention v9 (round-9/11 verbatim): reg-staged padded chunk-major LDS ----------------
__global__ __launch_bounds__(256, 4)
void attn_kernel(const u16* __restrict__ Q, const u16* __restrict__ Kk,
                 const u16* __restrict__ Vt, u16* __restrict__ Out) {
  int bid = blockIdx.x;
  int swz = (bid & 7) * 128 + (bid >> 3);  // XCD-chunked: each XCD owns 8 heads (4MB = L2)
  int bh = swz >> 4;
  int qt = swz & 15;
  int b = bh >> 4, h = bh & 15;
  int t = threadIdx.x;
  int wave = t >> 6, lane = t & 63;
  int l31 = lane & 31, hi = lane >> 5;

  __shared__ u16 lK[2][520 * 8];  // 8 chunks * 65 (64 rows + 1 pad) 16B slots
  __shared__ u16 lV[2][520 * 8];

  const u16* Qh = Q + (size_t)bh * SEQ * 64;
  const u16* Kh = Kk + (size_t)bh * SEQ * 64;
  const u16* Vh = Vt + (size_t)bh * 64 * SEQ;
  int q0w = qt * 128 + wave * 32;

  bf16x8 qf[4];
#pragma unroll
  for (int dc = 0; dc < 4; ++dc)
    qf[dc] = *reinterpret_cast<const bf16x8*>(
        &Qh[(size_t)(q0w + l31) * 64 + dc * 16 + hi * 8]);

  f32x16 oacc[2];
#pragma unroll
  for (int db = 0; db < 2; ++db)
#pragma unroll
    for (int r = 0; r < 16; ++r) oacc[db][r] = 0.f;
  float dn = 0.f;

  bf16x8 kreg[2], vreg[2];
  auto stage_load = [&](int kt) {
#pragma unroll
    for (int p = 0; p < 2; ++p) {
      int u = p * 256 + t;
      int r = u >> 3, c = u & 7;
      kreg[p] = *reinterpret_cast<const bf16x8*>(&Kh[(size_t)(kt * 64 + r) * 64 + c * 8]);
      vreg[p] = *reinterpret_cast<const bf16x8*>(&Vh[(size_t)r * SEQ + kt * 64 + c * 8]);
    }
  };
  auto stage_write = [&](int buf) {
#pragma unroll
    for (int p = 0; p < 2; ++p) {
      int u = p * 256 + t;
      int r = u >> 3, c = u & 7;
      *reinterpret_cast<bf16x8*>(&lK[buf][(c * 65 + r) * 8]) = kreg[p];
      *reinterpret_cast<bf16x8*>(&lV[buf][(c * 65 + r) * 8]) = vreg[p];
    }
  };

  union PF { u32 w[4]; bf16x8 v; };
  int cur = 0;
  stage_load(0);
  stage_write(0);
  __syncthreads();
  for (int kt = 0; kt < SEQ / 64; ++kt) {
    if (kt + 1 < SEQ / 64) stage_load(kt + 1);  // in flight across compute (T14)

    f32x16 s[2];
#pragma unroll
    for (int cb = 0; cb < 2; ++cb)
#pragma unroll
      for (int r = 0; r < 16; ++r) s[cb][r] = 0.f;
    __builtin_amdgcn_s_setprio(1);
#pragma unroll
    for (int cb = 0; cb < 2; ++cb) {
#pragma unroll
      for (int dc = 0; dc < 4; ++dc) {
        bf16x8 kf = *reinterpret_cast<const bf16x8*>(
            &lK[cur][((dc * 2 + hi) * 65 + cb * 32 + l31) * 8]);
        s[cb] = __builtin_amdgcn_mfma_f32_32x32x16_bf16(kf, qf[dc], s[cb], 0, 0, 0);
      }
    }
    __builtin_amdgcn_s_setprio(0);

    PF pa[2][2];
#pragma unroll
    for (int cb = 0; cb < 2; ++cb) {
#pragma unroll
      for (int r = 0; r < 16; ++r) {
        float e = __builtin_amdgcn_exp2f(s[cb][r]);
        s[cb][r] = e;
        dn += e;
      }
#pragma unroll
      for (int c = 0; c < 2; ++c) {
        u32 u0 = f2u(s[cb][8 * c + 0]) + 0x8000u;
        u32 u1 = f2u(s[cb][8 * c + 1]) + 0x8000u;
        u32 u2 = f2u(s[cb][8 * c + 2]) + 0x8000u;
        u32 u3 = f2u(s[cb][8 * c + 3]) + 0x8000u;
        u32 u4 = f2u(s[cb][8 * c + 4]) + 0x8000u;
        u32 u5 = f2u(s[cb][8 * c + 5]) + 0x8000u;
        u32 u6 = f2u(s[cb][8 * c + 6]) + 0x8000u;
        u32 u7 = f2u(s[cb][8 * c + 7]) + 0x8000u;
        u32 a1 = __builtin_amdgcn_perm(u1, u0, 0x07060302);  // bf16(e1)<<16 | bf16(e0)
        u32 a2 = __builtin_amdgcn_perm(u3, u2, 0x07060302);
        u32 b1 = __builtin_amdgcn_perm(u5, u4, 0x07060302);
        u32 b2 = __builtin_amdgcn_perm(u7, u6, 0x07060302);
        asm("v_permlane32_swap_b32 %0, %1" : "+v"(a1), "+v"(b1));
        asm("v_permlane32_swap_b32 %0, %1" : "+v"(a2), "+v"(b2));
        pa[cb][c].w[0] = a1; pa[cb][c].w[1] = a2;
        pa[cb][c].w[2] = b1; pa[cb][c].w[3] = b2;
      }
    }

    __builtin_amdgcn_s_setprio(1);
#pragma unroll
    for (int cb = 0; cb < 2; ++cb)
#pragma unroll
      for (int c = 0; c < 2; ++c)
#pragma unroll
        for (int db = 0; db < 2; ++db) {
          bf16x8 vf = *reinterpret_cast<const bf16x8*>(
              &lV[cur][((cb * 4 + c * 2 + hi) * 65 + db * 32 + l31) * 8]);
          oacc[db] = __builtin_amdgcn_mfma_f32_32x32x16_bf16(pa[cb][c].v, vf, oacc[db], 0, 0, 0);
        }
    __builtin_amdgcn_s_setprio(0);

    if (kt + 1 < SEQ / 64) stage_write(cur ^ 1);  // implicit vmcnt wait lands here
    __syncthreads();
    cur ^= 1;
  }

  dn += __shfl_xor(dn, 32);
#pragma unroll
  for (int r = 0; r < 16; ++r) {
    int qrel = (r & 3) + 8 * (r >> 2) + 4 * hi;
    float dfull = __shfl(dn, qrel);
    float inv = __builtin_amdgcn_rcpf(dfull);
    int q = q0w + qrel;
#pragma unroll
    for (int db = 0; db < 2; ++db) {
      int d = db * 32 + l31;
      Out[(size_t)(b * SEQ + q) * EMB + h * 64 + d] = f2bf(oacc[db][r] * inv);
    }
  }
}

// ---------------- launch ----------------
extern "C" void kernel_launch(void* const* d_in, const int* in_sizes, int n_in,
                              void* d_out, int out_size, void* d_ws, size_t ws_size,
                              hipStream_t stream) {
  const float* x = (const float*)d_in[0];
  const float* bqkv = (const float*)d_in[2];
  const float* bout = (const float*)d_in[4];
  float* out = (float*)d_out;

  char* ws = (char*)d_ws;
  size_t off = 0;
  auto alloc = [&](size_t bytes) {
    void* p = ws + off;
    off += (bytes + 255) & ~(size_t)255;
    return p;
  };
  u16* xb    = (u16*)alloc((size_t)MTOT * EMB * 2);
  u16* wqkvb = (u16*)alloc((size_t)3 * EMB * EMB * 2);
  u16* woutb = (u16*)alloc((size_t)EMB * EMB * 2);
  u16* Qb    = (u16*)alloc((size_t)64 * SEQ * HD * 2);
  u16* Kb    = (u16*)alloc((size_t)64 * SEQ * HD * 2);
  u16* Vtb   = (u16*)alloc((size_t)64 * HD * SEQ * 2);
  u16* aout  = (u16*)alloc((size_t)MTOT * EMB * 2);
  float* tab2 = (float*)alloc((size_t)SEQ * 32 * 2 * 4);
  (void)ws_size; (void)in_sizes; (void)n_in; (void)out_size;

  prep_kernel<<<4096, 256, 0, stream>>>(x, (const float*)d_in[1], (const float*)d_in[3],
                                        xb, wqkvb, woutb, tab2);
  gemm_qkv_rope<<<64 * 24, 256, 0, stream>>>(xb, wqkvb, bqkv, tab2, Qb, Kb, Vtb);
  attn_kernel<<<64 * 16, 256, 0, stream>>>(Qb, Kb, Vtb, aout);
  gemm_bt_f32<<<64 * 8, 256, 0, stream>>>(aout, woutb, bout, out, EMB, 8);
}

// Round 14
// 171.039 us; speedup vs baseline: 1.1797x; 1.0301x over previous
//
#include <hip/hip_runtime.h>
#include <hip/hip_bf16.h>
#include <cstdint>
#include <cstddef>

#define SEQ 2048
#define NBATCH 4
#define EMB 1024
#define NH 16
#define HD 64
#define MTOT (NBATCH * SEQ)   // 8192

typedef __attribute__((ext_vector_type(8))) short bf16x8;
typedef __attribute__((ext_vector_type(4))) float f32x4;
typedef __attribute__((ext_vector_type(16))) float f32x16;
typedef unsigned short u16;
typedef unsigned int u32;

__device__ __forceinline__ float bf2f(u16 v) {
  union { u32 u; float f; } c; c.u = ((u32)v) << 16; return c.f;
}
__device__ __forceinline__ u16 f2bf(float f) {
  union { float f; u32 u; } c; c.f = f;
  u32 u = c.u;
  return (u16)((u + 0x7FFFu + ((u >> 16) & 1u)) >> 16);
}
__device__ __forceinline__ u32 f2u(float f) {
  union { float f; u32 u; } c; c.f = f; return c.u;
}

// ---------------- fused prep: casts (x, W_qkv, W_out) + RoPE table ----------------
__global__ void prep_kernel(const float* __restrict__ x, const float* __restrict__ wqkv,
                            const float* __restrict__ wout,
                            u16* __restrict__ xb, u16* __restrict__ wqkvb,
                            u16* __restrict__ woutb, float* __restrict__ tab2) {
  int tid = blockIdx.x * blockDim.x + threadIdx.x;
  int stride = gridDim.x * blockDim.x;
  for (int i = tid; i < MTOT * EMB / 4; i += stride) {
    float4 v = reinterpret_cast<const float4*>(x)[i];
    ushort4 o;
    o.x = f2bf(v.x); o.y = f2bf(v.y); o.z = f2bf(v.z); o.w = f2bf(v.w);
    reinterpret_cast<ushort4*>(xb)[i] = o;
  }
  for (int i = tid; i < 3 * EMB * EMB / 4; i += stride) {
    float4 v = reinterpret_cast<const float4*>(wqkv)[i];
    ushort4 o;
    o.x = f2bf(v.x); o.y = f2bf(v.y); o.z = f2bf(v.z); o.w = f2bf(v.w);
    reinterpret_cast<ushort4*>(wqkvb)[i] = o;
  }
  for (int i = tid; i < EMB * EMB / 4; i += stride) {
    float4 v = reinterpret_cast<const float4*>(wout)[i];
    ushort4 o;
    o.x = f2bf(v.x); o.y = f2bf(v.y); o.z = f2bf(v.z); o.w = f2bf(v.w);
    reinterpret_cast<ushort4*>(woutb)[i] = o;
  }
  for (int i = tid; i < SEQ * 32; i += stride) {
    int n = i >> 5, j = i & 31;
    float invf = 1.0f / powf(10000.0f, (float)(2 * j) / 64.0f);
    float ang = (float)n * invf;
    tab2[2 * i] = cosf(ang);
    tab2[2 * i + 1] = sinf(ang);
  }
}

// ---------------- async global->LDS helper (16B) ----------------
__device__ __forceinline__ void gld_lds16(const u16* g, u16* l) {
  __builtin_amdgcn_global_load_lds((const __attribute__((address_space(1))) void*)g,
                                   (__attribute__((address_space(3))) void*)l, 16, 0, 0);
}

// ---------------- GEMM: C[M,N] = A[M,K] * Bw[N,K]^T + bias (out-proj, fp32 out) ----------------
// XCD-locality swizzle: bm%8 == XCD -> each A row-tile is fetched by exactly one XCD's L2.
__global__ __launch_bounds__(256, 2)
void gemm_bt_f32(const u16* __restrict__ A, const u16* __restrict__ Bw,
                 const float* __restrict__ bias, float* __restrict__ Cout,
                 int N, int tiles_n) {
  __shared__ u16 lA[128 * 64];
  __shared__ u16 lB[128 * 64];
  const int K = 1024;
  int g = blockIdx.x;
  int xcd = g & 7, idx = g >> 3;
  int bm = (idx & 7) * 8 + xcd;     // bm%8 == xcd (64 bm values per 8 XCDs)
  int bn = idx >> 3;                // 0..tiles_n-1
  int t = threadIdx.x;
  int wave = t >> 6, lane = t & 63;
  int wm = wave >> 1, wn = wave & 1;
  int l15 = lane & 15, l4 = lane >> 4;

  f32x4 acc[4][4];
#pragma unroll
  for (int i = 0; i < 4; ++i)
#pragma unroll
    for (int j = 0; j < 4; ++j) acc[i][j] = (f32x4){0.f, 0.f, 0.f, 0.f};

  int su[4], sr[4], sc[4];
#pragma unroll
  for (int i = 0; i < 4; ++i) {
    int u = (i * 4 + wave) * 64 + lane;
    su[i] = u;
    sr[i] = u >> 3;
    sc[i] = (u & 7) ^ (sr[i] & 7);
  }

  for (int kt = 0; kt < K / 64; ++kt) {
    if (kt) __syncthreads();
#pragma unroll
    for (int i = 0; i < 4; ++i) {
      gld_lds16(A + (size_t)(bm * 128 + sr[i]) * K + kt * 64 + sc[i] * 8, &lA[su[i] * 8]);
      gld_lds16(Bw + (size_t)(bn * 128 + sr[i]) * K + kt * 64 + sc[i] * 8, &lB[su[i] * 8]);
    }
    __syncthreads();
#pragma unroll
    for (int ks = 0; ks < 2; ++ks) {
      bf16x8 af[4], bfr[4];
#pragma unroll
      for (int mb = 0; mb < 4; ++mb) {
        int r = wm * 64 + mb * 16 + l15;
        int cc = (ks * 4 + l4) ^ (r & 7);
        af[mb] = *reinterpret_cast<const bf16x8*>(&lA[r * 64 + cc * 8]);
      }
#pragma unroll
      for (int nb = 0; nb < 4; ++nb) {
        int r = wn * 64 + nb * 16 + l15;
        int cc = (ks * 4 + l4) ^ (r & 7);
        bfr[nb] = *reinterpret_cast<const bf16x8*>(&lB[r * 64 + cc * 8]);
      }
#pragma unroll
      for (int mb = 0; mb < 4; ++mb)
#pragma unroll
        for (int nb = 0; nb < 4; ++nb)
          acc[mb][nb] = __builtin_amdgcn_mfma_f32_16x16x32_bf16(af[mb], bfr[nb], acc[mb][nb], 0, 0, 0);
    }
  }

#pragma unroll
  for (int mb = 0; mb < 4; ++mb)
#pragma unroll
    for (int nb = 0; nb < 4; ++nb) {
      int row0 = bm * 128 + wm * 64 + mb * 16 + l4 * 4;
      int col = bn * 128 + wn * 64 + nb * 16 + l15;
      float bv = bias[col];
#pragma unroll
      for (int r = 0; r < 4; ++r)
        Cout[(size_t)(row0 + r) * N + col] = acc[mb][nb][r] + bv;
    }
}

// ---------------- fused QKV GEMM + bias + RoPE + scatter (coalesced Q/K stores) ----------------
__global__ __launch_bounds__(256, 2)
void gemm_qkv_rope(const u16* __restrict__ A, const u16* __restrict__ Bw,
                   const float* __restrict__ bias, const float* __restrict__ tab2,
                   u16* __restrict__ Qb, u16* __restrict__ Kb, u16* __restrict__ Vtb) {
  __shared__ u16 lA[128 * 64];
  __shared__ u16 lB[128 * 64];
  const int K = 1024;
  int g = blockIdx.x;
  int xcd = g & 7, idx = g >> 3;
  int bm = (idx & 7) * 8 + xcd;     // 0..63 ; bm%8 == xcd
  int bn = idx >> 3;                // 0..23
  int t = threadIdx.x;
  int wave = t >> 6, lane = t & 63;
  int wm = wave >> 1, wn = wave & 1;
  int l15 = lane & 15, l4 = lane >> 4;

  f32x4 acc[4][4];
#pragma unroll
  for (int i = 0; i < 4; ++i)
#pragma unroll
    for (int j = 0; j < 4; ++j) acc[i][j] = (f32x4){0.f, 0.f, 0.f, 0.f};

  int su[4], sr[4], sc[4];
#pragma unroll
  for (int i = 0; i < 4; ++i) {
    int u = (i * 4 + wave) * 64 + lane;
    su[i] = u;
    sr[i] = u >> 3;
    sc[i] = (u & 7) ^ (sr[i] & 7);
  }
  // B row permutation: within each 64-row half, LDS row rr holds weight row tau(rr)
  int tauB[4];
#pragma unroll
  for (int i = 0; i < 4; ++i) {
    int rr = sr[i] & 63;
    tauB[i] = (sr[i] & 64) | (rr & 32) | ((rr & 15) << 1) | ((rr >> 4) & 1);
  }

  for (int kt = 0; kt < K / 64; ++kt) {
    if (kt) __syncthreads();
#pragma unroll
    for (int i = 0; i < 4; ++i) {
      gld_lds16(A + (size_t)(bm * 128 + sr[i]) * K + kt * 64 + sc[i] * 8, &lA[su[i] * 8]);
      gld_lds16(Bw + (size_t)(bn * 128 + tauB[i]) * K + kt * 64 + sc[i] * 8, &lB[su[i] * 8]);
    }
    __syncthreads();
#pragma unroll
    for (int ks = 0; ks < 2; ++ks) {
      bf16x8 af[4], bfr[4];
#pragma unroll
      for (int mb = 0; mb < 4; ++mb) {
        int r = wm * 64 + mb * 16 + l15;
        int cc = (ks * 4 + l4) ^ (r & 7);
        af[mb] = *reinterpret_cast<const bf16x8*>(&lA[r * 64 + cc * 8]);
      }
#pragma unroll
      for (int nb = 0; nb < 4; ++nb) {
        int r = wn * 64 + nb * 16 + l15;
        int cc = (ks * 4 + l4) ^ (r & 7);
        bfr[nb] = *reinterpret_cast<const bf16x8*>(&lB[r * 64 + cc * 8]);
      }
#pragma unroll
      for (int mb = 0; mb < 4; ++mb)
#pragma unroll
        for (int nb = 0; nb < 4; ++nb)
          acc[mb][nb] = __builtin_amdgcn_mfma_f32_16x16x32_bf16(af[mb], bfr[nb], acc[mb][nb], 0, 0, 0);
    }
  }

  // ---- fused epilogue ----
  int type = bn >> 3;            // 0=q, 1=k, 2=v
  int h = (bn * 2 + wn) & 15;    // head
  int colbase = bn * 128 + wn * 64;
  float bv[4];
#pragma unroll
  for (int nb = 0; nb < 4; ++nb)
    bv[nb] = bias[colbase + 32 * (nb >> 1) + 2 * l15 + (nb & 1)];

  if (type < 2) {
    u16* dst0 = (type == 0) ? Qb : Kb;
    float qs = (type == 0) ? 0.1803368801111163f : 1.0f;  // (1/8)*log2(e) folded into q
#pragma unroll
    for (int mb = 0; mb < 4; ++mb) {
      int row0 = bm * 128 + wm * 64 + mb * 16 + l4 * 4;
#pragma unroll
      for (int r = 0; r < 4; ++r) {
        int row = row0 + r;
        int bb = row >> 11, nl = row & 2047;
        float4 cs4 = *reinterpret_cast<const float4*>(tab2 + (size_t)nl * 64 + 4 * l15);
        float a0 = acc[mb][0][r] + bv[0];   // d = 2l15
        float a1 = acc[mb][1][r] + bv[1];   // d = 2l15+1
        float a2 = acc[mb][2][r] + bv[2];   // d = 2l15+32
        float a3 = acc[mb][3][r] + bv[3];   // d = 2l15+33
        float o0 = (a0 * cs4.x - a2 * cs4.y) * qs;
        float o2 = (a2 * cs4.x + a0 * cs4.y) * qs;
        float o1 = (a1 * cs4.z - a3 * cs4.w) * qs;
        float o3 = (a3 * cs4.z + a1 * cs4.w) * qs;
        u16* dst = dst0 + ((size_t)(bb * 16 + h) * SEQ + nl) * 64;
        u32 lo = (u32)f2bf(o0) | ((u32)f2bf(o1) << 16);
        u32 hi2 = (u32)f2bf(o2) | ((u32)f2bf(o3) << 16);
        *reinterpret_cast<u32*>(&dst[2 * l15]) = lo;
        *reinterpret_cast<u32*>(&dst[32 + 2 * l15]) = hi2;
      }
    }
  } else {
#pragma unroll
    for (int mb = 0; mb < 4; ++mb) {
      int row0 = bm * 128 + wm * 64 + mb * 16 + l4 * 4;
      int bb = row0 >> 11, nl0 = row0 & 2047;
#pragma unroll
      for (int nb = 0; nb < 4; ++nb) {
        int d = 32 * (nb >> 1) + 2 * l15 + (nb & 1);
        ushort4 pk;
        pk.x = f2bf(acc[mb][nb][0] + bv[nb]);
        pk.y = f2bf(acc[mb][nb][1] + bv[nb]);
        pk.z = f2bf(acc[mb][nb][2] + bv[nb]);
        pk.w = f2bf(acc[mb][nb][3] + bv[nb]);
        *reinterpret_cast<ushort4*>(&Vtb[((size_t)(bb * 16 + h) * 64 + d) * SEQ + nl0]) = pk;
      }
    }
  }
}

// ---------------- attention v11: 64 q-rows/wave (256-row tile), zacc seeding ----------------
// 256 threads = 4 waves, 64 q-rows each; grid = 64 heads * 8 tiles = 512 blocks = 2/CU.
// ds_read, staging traffic, and barrier count per unit work all HALVED vs 32-row shape
// (round 3 proved the shape at 81us with worse LDS+pack). zacc seeds each QK chain's
// first MFMA C-operand -> no per-iter S zero-init movs (-64 VALU/iter).
__global__ __launch_bounds__(256, 2)
void attn_kernel(const u16* __restrict__ Q, const u16* __restrict__ Kk,
                 const u16* __restrict__ Vt, u16* __restrict__ Out) {
  int bid = blockIdx.x;
  int swz = (bid & 7) * 64 + (bid >> 3);  // 512 = 8 XCD x 64 ; each XCD owns 8 heads
  int bh = swz >> 3;
  int qt = swz & 7;
  int b = bh >> 4, h = bh & 15;
  int t = threadIdx.x;
  int wave = t >> 6, lane = t & 63;
  int l31 = lane & 31, hi = lane >> 5;

  __shared__ u16 lK[2][520 * 8];  // 8 chunks * 65 (64 rows + 1 pad) 16B slots
  __shared__ u16 lV[2][520 * 8];

  const u16* Qh = Q + (size_t)bh * SEQ * 64;
  const u16* Kh = Kk + (size_t)bh * SEQ * 64;
  const u16* Vh = Vt + (size_t)bh * 64 * SEQ;
  int q0w = qt * 256 + wave * 64;

  bf16x8 qf[2][4];
#pragma unroll
  for (int qb = 0; qb < 2; ++qb)
#pragma unroll
    for (int dc = 0; dc < 4; ++dc)
      qf[qb][dc] = *reinterpret_cast<const bf16x8*>(
          &Qh[(size_t)(q0w + qb * 32 + l31) * 64 + dc * 16 + hi * 8]);

  f32x16 oacc[2][2];
#pragma unroll
  for (int qb = 0; qb < 2; ++qb)
#pragma unroll
    for (int db = 0; db < 2; ++db)
#pragma unroll
      for (int r = 0; r < 16; ++r) oacc[qb][db][r] = 0.f;
  f32x16 zacc;  // loop-invariant zeros: C-operand for each QK chain's first MFMA
#pragma unroll
  for (int r = 0; r < 16; ++r) zacc[r] = 0.f;
  float dn[2] = {0.f, 0.f};

  bf16x8 kreg[2], vreg[2];
  auto stage_load = [&](int kt) {
#pragma unroll
    for (int p = 0; p < 2; ++p) {
      int u = p * 256 + t;
      int r = u >> 3, c = u & 7;
      kreg[p] = *reinterpret_cast<const bf16x8*>(&Kh[(size_t)(kt * 64 + r) * 64 + c * 8]);
      vreg[p] = *reinterpret_cast<const bf16x8*>(&Vh[(size_t)r * SEQ + kt * 64 + c * 8]);
    }
  };
  auto stage_write = [&](int buf) {
#pragma unroll
    for (int p = 0; p < 2; ++p) {
      int u = p * 256 + t;
      int r = u >> 3, c = u & 7;
      *reinterpret_cast<bf16x8*>(&lK[buf][(c * 65 + r) * 8]) = kreg[p];
      *reinterpret_cast<bf16x8*>(&lV[buf][(c * 65 + r) * 8]) = vreg[p];
    }
  };

  union PF { u32 w[4]; bf16x8 v; };
  int cur = 0;
  stage_load(0);
  stage_write(0);
  __syncthreads();
  for (int kt = 0; kt < SEQ / 64; ++kt) {
    if (kt + 1 < SEQ / 64) stage_load(kt + 1);  // in flight across compute (T14)

    // ---- QK^T swapped: S^T[k][q] ; lane: q = l31, k = cb*32 + (r&3)+8*(r>>2)+4*hi
    f32x16 s[2][2];
    __builtin_amdgcn_s_setprio(1);
#pragma unroll
    for (int cb = 0; cb < 2; ++cb) {
#pragma unroll
      for (int dc = 0; dc < 4; ++dc) {
        bf16x8 kf = *reinterpret_cast<const bf16x8*>(
            &lK[cur][((dc * 2 + hi) * 65 + cb * 32 + l31) * 8]);
        s[0][cb] = __builtin_amdgcn_mfma_f32_32x32x16_bf16(kf, qf[0][dc], dc ? s[0][cb] : zacc, 0, 0, 0);
        s[1][cb] = __builtin_amdgcn_mfma_f32_32x32x16_bf16(kf, qf[1][dc], dc ? s[1][cb] : zacc, 0, 0, 0);
      }
    }
    __builtin_amdgcn_s_setprio(0);

    // ---- softmax in-register (per qb to cap live registers): exp2, RHU + v_perm pack
    PF pa[2][2][2];  // [qb][cb][c]
#pragma unroll
    for (int qb = 0; qb < 2; ++qb)
#pragma unroll
      for (int cb = 0; cb < 2; ++cb) {
#pragma unroll
        for (int r = 0; r < 16; ++r) {
          float e = __builtin_amdgcn_exp2f(s[qb][cb][r]);
          s[qb][cb][r] = e;
          dn[qb] += e;
        }
#pragma unroll
        for (int c = 0; c < 2; ++c) {
          u32 u0 = f2u(s[qb][cb][8 * c + 0]) + 0x8000u;
          u32 u1 = f2u(s[qb][cb][8 * c + 1]) + 0x8000u;
          u32 u2 = f2u(s[qb][cb][8 * c + 2]) + 0x8000u;
          u32 u3 = f2u(s[qb][cb][8 * c + 3]) + 0x8000u;
          u32 u4 = f2u(s[qb][cb][8 * c + 4]) + 0x8000u;
          u32 u5 = f2u(s[qb][cb][8 * c + 5]) + 0x8000u;
          u32 u6 = f2u(s[qb][cb][8 * c + 6]) + 0x8000u;
          u32 u7 = f2u(s[qb][cb][8 * c + 7]) + 0x8000u;
          u32 a1 = __builtin_amdgcn_perm(u1, u0, 0x07060302);  // bf16(e1)<<16 | bf16(e0)
          u32 a2 = __builtin_amdgcn_perm(u3, u2, 0x07060302);
          u32 b1 = __builtin_amdgcn_perm(u5, u4, 0x07060302);
          u32 b2 = __builtin_amdgcn_perm(u7, u6, 0x07060302);
          asm("v_permlane32_swap_b32 %0, %1" : "+v"(a1), "+v"(b1));
          asm("v_permlane32_swap_b32 %0, %1" : "+v"(a2), "+v"(b2));
          pa[qb][cb][c].w[0] = a1; pa[qb][cb][c].w[1] = a2;
          pa[qb][cb][c].w[2] = b1; pa[qb][cb][c].w[3] = b2;
        }
      }

    // ---- PV: O[q][d] ; A = P (regs), B = V from LDS; each vf serves both qb
    __builtin_amdgcn_s_setprio(1);
#pragma unroll
    for (int cb = 0; cb < 2; ++cb)
#pragma unroll
      for (int c = 0; c < 2; ++c)
#pragma unroll
        for (int db = 0; db < 2; ++db) {
          bf16x8 vf = *reinterpret_cast<const bf16x8*>(
              &lV[cur][((cb * 4 + c * 2 + hi) * 65 + db * 32 + l31) * 8]);
          oacc[0][db] = __builtin_amdgcn_mfma_f32_32x32x16_bf16(pa[0][cb][c].v, vf, oacc[0][db], 0, 0, 0);
          oacc[1][db] = __builtin_amdgcn_mfma_f32_32x32x16_bf16(pa[1][cb][c].v, vf, oacc[1][db], 0, 0, 0);
        }
    __builtin_amdgcn_s_setprio(0);

    if (kt + 1 < SEQ / 64) stage_write(cur ^ 1);  // implicit vmcnt wait lands here
    __syncthreads();
    cur ^= 1;
  }

  // ---- epilogue: combine denom halves, normalize, store
#pragma unroll
  for (int qb = 0; qb < 2; ++qb) dn[qb] += __shfl_xor(dn[qb], 32);
#pragma unroll
  for (int qb = 0; qb < 2; ++qb)
#pragma unroll
    for (int r = 0; r < 16; ++r) {
      int qrel = (r & 3) + 8 * (r >> 2) + 4 * hi;
      float dfull = __shfl(dn[qb], qrel);
      float inv = __builtin_amdgcn_rcpf(dfull);
      int q = q0w + qb * 32 + qrel;
#pragma unroll
      for (int db = 0; db < 2; ++db) {
        int d = db * 32 + l31;
        Out[(size_t)(b * SEQ + q) * EMB + h * 64 + d] = f2bf(oacc[qb][db][r] * inv);
      }
    }
}

// ---------------- launch ----------------
extern "C" void kernel_launch(void* const* d_in, const int* in_sizes, int n_in,
                              void* d_out, int out_size, void* d_ws, size_t ws_size,
                              hipStream_t stream) {
  const float* x = (const float*)d_in[0];
  const float* bqkv = (const float*)d_in[2];
  const float* bout = (const float*)d_in[4];
  float* out = (float*)d_out;

  char* ws = (char*)d_ws;
  size_t off = 0;
  auto alloc = [&](size_t bytes) {
    void* p = ws + off;
    off += (bytes + 255) & ~(size_t)255;
    return p;
  };
  u16* xb    = (u16*)alloc((size_t)MTOT * EMB * 2);
  u16* wqkvb = (u16*)alloc((size_t)3 * EMB * EMB * 2);
  u16* woutb = (u16*)alloc((size_t)EMB * EMB * 2);
  u16* Qb    = (u16*)alloc((size_t)64 * SEQ * HD * 2);
  u16* Kb    = (u16*)alloc((size_t)64 * SEQ * HD * 2);
  u16* Vtb   = (u16*)alloc((size_t)64 * HD * SEQ * 2);
  u16* aout  = (u16*)alloc((size_t)MTOT * EMB * 2);
  float* tab2 = (float*)alloc((size_t)SEQ * 32 * 2 * 4);
  (void)ws_size; (void)in_sizes; (void)n_in; (void)out_size;

  prep_kernel<<<4096, 256, 0, stream>>>(x, (const float*)d_in[1], (const float*)d_in[3],
                                        xb, wqkvb, woutb, tab2);
  gemm_qkv_rope<<<64 * 24, 256, 0, stream>>>(xb, wqkvb, bqkv, tab2, Qb, Kb, Vtb);
  attn_kernel<<<64 * 8, 256, 0, stream>>>(Qb, Kb, Vtb, aout);
  gemm_bt_f32<<<64 * 8, 256, 0, stream>>>(aout, woutb, bout, out, EMB, 8);
}

// Round 15
// 169.977 us; speedup vs baseline: 1.1870x; 1.0063x over previous
//
#include <hip/hip_runtime.h>
#include <hip/hip_bf16.h>
#include <cstdint>
#include <cstddef>

#define SEQ 2048
#define NBATCH 4
#define EMB 1024
#define NH 16
#define HD 64
#define MTOT (NBATCH * SEQ)   // 8192

typedef __attribute__((ext_vector_type(8))) short bf16x8;
typedef __attribute__((ext_vector_type(4))) float f32x4;
typedef __attribute__((ext_vector_type(16))) float f32x16;
typedef unsigned short u16;
typedef unsigned int u32;

__device__ __forceinline__ float bf2f(u16 v) {
  union { u32 u; float f; } c; c.u = ((u32)v) << 16; return c.f;
}
__device__ __forceinline__ u16 f2bf(float f) {
  union { float f; u32 u; } c; c.f = f;
  u32 u = c.u;
  return (u16)((u + 0x7FFFu + ((u >> 16) & 1u)) >> 16);
}
__device__ __forceinline__ u32 f2u(float f) {
  union { float f; u32 u; } c; c.f = f; return c.u;
}

// ---------------- fused prep: casts (x, W_qkv, W_out) + RoPE table ----------------
__global__ void prep_kernel(const float* __restrict__ x, const float* __restrict__ wqkv,
                            const float* __restrict__ wout,
                            u16* __restrict__ xb, u16* __restrict__ wqkvb,
                            u16* __restrict__ woutb, float* __restrict__ tab2) {
  int tid = blockIdx.x * blockDim.x + threadIdx.x;
  int stride = gridDim.x * blockDim.x;
  for (int i = tid; i < MTOT * EMB / 4; i += stride) {
    float4 v = reinterpret_cast<const float4*>(x)[i];
    ushort4 o;
    o.x = f2bf(v.x); o.y = f2bf(v.y); o.z = f2bf(v.z); o.w = f2bf(v.w);
    reinterpret_cast<ushort4*>(xb)[i] = o;
  }
  for (int i = tid; i < 3 * EMB * EMB / 4; i += stride) {
    float4 v = reinterpret_cast<const float4*>(wqkv)[i];
    ushort4 o;
    o.x = f2bf(v.x); o.y = f2bf(v.y); o.z = f2bf(v.z); o.w = f2bf(v.w);
    reinterpret_cast<ushort4*>(wqkvb)[i] = o;
  }
  for (int i = tid; i < EMB * EMB / 4; i += stride) {
    float4 v = reinterpret_cast<const float4*>(wout)[i];
    ushort4 o;
    o.x = f2bf(v.x); o.y = f2bf(v.y); o.z = f2bf(v.z); o.w = f2bf(v.w);
    reinterpret_cast<ushort4*>(woutb)[i] = o;
  }
  for (int i = tid; i < SEQ * 32; i += stride) {
    int n = i >> 5, j = i & 31;
    float invf = 1.0f / powf(10000.0f, (float)(2 * j) / 64.0f);
    float ang = (float)n * invf;
    tab2[2 * i] = cosf(ang);
    tab2[2 * i + 1] = sinf(ang);
  }
}

// ---------------- async global->LDS helper (16B) ----------------
__device__ __forceinline__ void gld_lds16(const u16* g, u16* l) {
  __builtin_amdgcn_global_load_lds((const __attribute__((address_space(1))) void*)g,
                                   (__attribute__((address_space(3))) void*)l, 16, 0, 0);
}

// ---------------- GEMM: C[M,N] = A[M,K] * Bw[N,K]^T + bias (out-proj, fp32 out) ----------------
// XCD-locality swizzle: bm%8 == XCD -> each A row-tile is fetched by exactly one XCD's L2.
__global__ __launch_bounds__(256, 2)
void gemm_bt_f32(const u16* __restrict__ A, const u16* __restrict__ Bw,
                 const float* __restrict__ bias, float* __restrict__ Cout,
                 int N, int tiles_n) {
  __shared__ u16 lA[128 * 64];
  __shared__ u16 lB[128 * 64];
  const int K = 1024;
  int g = blockIdx.x;
  int xcd = g & 7, idx = g >> 3;
  int bm = (idx & 7) * 8 + xcd;     // bm%8 == xcd (64 bm values per 8 XCDs)
  int bn = idx >> 3;                // 0..tiles_n-1
  int t = threadIdx.x;
  int wave = t >> 6, lane = t & 63;
  int wm = wave >> 1, wn = wave & 1;
  int l15 = lane & 15, l4 = lane >> 4;

  f32x4 acc[4][4];
#pragma unroll
  for (int i = 0; i < 4; ++i)
#pragma unroll
    for (int j = 0; j < 4; ++j) acc[i][j] = (f32x4){0.f, 0.f, 0.f, 0.f};

  int su[4], sr[4], sc[4];
#pragma unroll
  for (int i = 0; i < 4; ++i) {
    int u = (i * 4 + wave) * 64 + lane;
    su[i] = u;
    sr[i] = u >> 3;
    sc[i] = (u & 7) ^ (sr[i] & 7);
  }

  for (int kt = 0; kt < K / 64; ++kt) {
    if (kt) __syncthreads();
#pragma unroll
    for (int i = 0; i < 4; ++i) {
      gld_lds16(A + (size_t)(bm * 128 + sr[i]) * K + kt * 64 + sc[i] * 8, &lA[su[i] * 8]);
      gld_lds16(Bw + (size_t)(bn * 128 + sr[i]) * K + kt * 64 + sc[i] * 8, &lB[su[i] * 8]);
    }
    __syncthreads();
#pragma unroll
    for (int ks = 0; ks < 2; ++ks) {
      bf16x8 af[4], bfr[4];
#pragma unroll
      for (int mb = 0; mb < 4; ++mb) {
        int r = wm * 64 + mb * 16 + l15;
        int cc = (ks * 4 + l4) ^ (r & 7);
        af[mb] = *reinterpret_cast<const bf16x8*>(&lA[r * 64 + cc * 8]);
      }
#pragma unroll
      for (int nb = 0; nb < 4; ++nb) {
        int r = wn * 64 + nb * 16 + l15;
        int cc = (ks * 4 + l4) ^ (r & 7);
        bfr[nb] = *reinterpret_cast<const bf16x8*>(&lB[r * 64 + cc * 8]);
      }
#pragma unroll
      for (int mb = 0; mb < 4; ++mb)
#pragma unroll
        for (int nb = 0; nb < 4; ++nb)
          acc[mb][nb] = __builtin_amdgcn_mfma_f32_16x16x32_bf16(af[mb], bfr[nb], acc[mb][nb], 0, 0, 0);
    }
  }

#pragma unroll
  for (int mb = 0; mb < 4; ++mb)
#pragma unroll
    for (int nb = 0; nb < 4; ++nb) {
      int row0 = bm * 128 + wm * 64 + mb * 16 + l4 * 4;
      int col = bn * 128 + wn * 64 + nb * 16 + l15;
      float bv = bias[col];
#pragma unroll
      for (int r = 0; r < 4; ++r)
        Cout[(size_t)(row0 + r) * N + col] = acc[mb][nb][r] + bv;
    }
}

// ---------------- fused QKV GEMM + bias + RoPE + scatter (coalesced Q/K stores) ----------------
__global__ __launch_bounds__(256, 2)
void gemm_qkv_rope(const u16* __restrict__ A, const u16* __restrict__ Bw,
                   const float* __restrict__ bias, const float* __restrict__ tab2,
                   u16* __restrict__ Qb, u16* __restrict__ Kb, u16* __restrict__ Vtb) {
  __shared__ u16 lA[128 * 64];
  __shared__ u16 lB[128 * 64];
  const int K = 1024;
  int g = blockIdx.x;
  int xcd = g & 7, idx = g >> 3;
  int bm = (idx & 7) * 8 + xcd;     // 0..63 ; bm%8 == xcd
  int bn = idx >> 3;                // 0..23
  int t = threadIdx.x;
  int wave = t >> 6, lane = t & 63;
  int wm = wave >> 1, wn = wave & 1;
  int l15 = lane & 15, l4 = lane >> 4;

  f32x4 acc[4][4];
#pragma unroll
  for (int i = 0; i < 4; ++i)
#pragma unroll
    for (int j = 0; j < 4; ++j) acc[i][j] = (f32x4){0.f, 0.f, 0.f, 0.f};

  int su[4], sr[4], sc[4];
#pragma unroll
  for (int i = 0; i < 4; ++i) {
    int u = (i * 4 + wave) * 64 + lane;
    su[i] = u;
    sr[i] = u >> 3;
    sc[i] = (u & 7) ^ (sr[i] & 7);
  }
  // B row permutation: within each 64-row half, LDS row rr holds weight row tau(rr)
  int tauB[4];
#pragma unroll
  for (int i = 0; i < 4; ++i) {
    int rr = sr[i] & 63;
    tauB[i] = (sr[i] & 64) | (rr & 32) | ((rr & 15) << 1) | ((rr >> 4) & 1);
  }

  for (int kt = 0; kt < K / 64; ++kt) {
    if (kt) __syncthreads();
#pragma unroll
    for (int i = 0; i < 4; ++i) {
      gld_lds16(A + (size_t)(bm * 128 + sr[i]) * K + kt * 64 + sc[i] * 8, &lA[su[i] * 8]);
      gld_lds16(Bw + (size_t)(bn * 128 + tauB[i]) * K + kt * 64 + sc[i] * 8, &lB[su[i] * 8]);
    }
    __syncthreads();
#pragma unroll
    for (int ks = 0; ks < 2; ++ks) {
      bf16x8 af[4], bfr[4];
#pragma unroll
      for (int mb = 0; mb < 4; ++mb) {
        int r = wm * 64 + mb * 16 + l15;
        int cc = (ks * 4 + l4) ^ (r & 7);
        af[mb] = *reinterpret_cast<const bf16x8*>(&lA[r * 64 + cc * 8]);
      }
#pragma unroll
      for (int nb = 0; nb < 4; ++nb) {
        int r = wn * 64 + nb * 16 + l15;
        int cc = (ks * 4 + l4) ^ (r & 7);
        bfr[nb] = *reinterpret_cast<const bf16x8*>(&lB[r * 64 + cc * 8]);
      }
#pragma unroll
      for (int mb = 0; mb < 4; ++mb)
#pragma unroll
        for (int nb = 0; nb < 4; ++nb)
          acc[mb][nb] = __builtin_amdgcn_mfma_f32_16x16x32_bf16(af[mb], bfr[nb], acc[mb][nb], 0, 0, 0);
    }
  }

  // ---- fused epilogue ----
  int type = bn >> 3;            // 0=q, 1=k, 2=v
  int h = (bn * 2 + wn) & 15;    // head
  int colbase = bn * 128 + wn * 64;
  float bv[4];
#pragma unroll
  for (int nb = 0; nb < 4; ++nb)
    bv[nb] = bias[colbase + 32 * (nb >> 1) + 2 * l15 + (nb & 1)];

  if (type < 2) {
    u16* dst0 = (type == 0) ? Qb : Kb;
    float qs = (type == 0) ? 0.1803368801111163f : 1.0f;  // (1/8)*log2(e) folded into q
#pragma unroll
    for (int mb = 0; mb < 4; ++mb) {
      int row0 = bm * 128 + wm * 64 + mb * 16 + l4 * 4;
#pragma unroll
      for (int r = 0; r < 4; ++r) {
        int row = row0 + r;
        int bb = row >> 11, nl = row & 2047;
        float4 cs4 = *reinterpret_cast<const float4*>(tab2 + (size_t)nl * 64 + 4 * l15);
        float a0 = acc[mb][0][r] + bv[0];   // d = 2l15
        float a1 = acc[mb][1][r] + bv[1];   // d = 2l15+1
        float a2 = acc[mb][2][r] + bv[2];   // d = 2l15+32
        float a3 = acc[mb][3][r] + bv[3];   // d = 2l15+33
        float o0 = (a0 * cs4.x - a2 * cs4.y) * qs;
        float o2 = (a2 * cs4.x + a0 * cs4.y) * qs;
        float o1 = (a1 * cs4.z - a3 * cs4.w) * qs;
        float o3 = (a3 * cs4.z + a1 * cs4.w) * qs;
        u16* dst = dst0 + ((size_t)(bb * 16 + h) * SEQ + nl) * 64;
        u32 lo = (u32)f2bf(o0) | ((u32)f2bf(o1) << 16);
        u32 hi2 = (u32)f2bf(o2) | ((u32)f2bf(o3) << 16);
        *reinterpret_cast<u32*>(&dst[2 * l15]) = lo;
        *reinterpret_cast<u32*>(&dst[32 + 2 * l15]) = hi2;
      }
    }
  } else {
#pragma unroll
    for (int mb = 0; mb < 4; ++mb) {
      int row0 = bm * 128 + wm * 64 + mb * 16 + l4 * 4;
      int bb = row0 >> 11, nl0 = row0 & 2047;
#pragma unroll
      for (int nb = 0; nb < 4; ++nb) {
        int d = 32 * (nb >> 1) + 2 * l15 + (nb & 1);
        ushort4 pk;
        pk.x = f2bf(acc[mb][nb][0] + bv[nb]);
        pk.y = f2bf(acc[mb][nb][1] + bv[nb]);
        pk.z = f2bf(acc[mb][nb][2] + bv[nb]);
        pk.w = f2bf(acc[mb][nb][3] + bv[nb]);
        *reinterpret_cast<ushort4*>(&Vtb[((size_t)(bb * 16 + h) * 64 + d) * SEQ + nl0]) = pk;
      }
    }
  }
}

// ---------------- attention v12: v9 per-wave shape, 8-wave blocks (halved staging) ----------------
// 512 threads = 8 waves, each wave 32 q-rows -> block covers 256 q-rows.
// grid = 64 heads * 8 tiles = 512 blocks; launch_bounds(512,4) -> 16 waves/CU (2 blocks/CU),
// same occupancy as v9 but each staged 64x64 K/V tile serves 2x the q-rows:
// L2 fetch, ds_writes, and barrier count per unit work all halved. Per-wave loop = v9 verbatim.
__global__ __launch_bounds__(512, 4)
void attn_kernel(const u16* __restrict__ Q, const u16* __restrict__ Kk,
                 const u16* __restrict__ Vt, u16* __restrict__ Out) {
  int bid = blockIdx.x;
  int swz = (bid & 7) * 64 + (bid >> 3);  // 512 = 8 XCD x 64 ; each XCD owns 8 heads
  int bh = swz >> 3;
  int qt = swz & 7;
  int b = bh >> 4, h = bh & 15;
  int t = threadIdx.x;
  int wave = t >> 6, lane = t & 63;
  int l31 = lane & 31, hi = lane >> 5;

  __shared__ u16 lK[2][520 * 8];  // 8 chunks * 65 (64 rows + 1 pad) 16B slots
  __shared__ u16 lV[2][520 * 8];

  const u16* Qh = Q + (size_t)bh * SEQ * 64;
  const u16* Kh = Kk + (size_t)bh * SEQ * 64;
  const u16* Vh = Vt + (size_t)bh * 64 * SEQ;
  int q0w = qt * 256 + wave * 32;

  bf16x8 qf[4];
#pragma unroll
  for (int dc = 0; dc < 4; ++dc)
    qf[dc] = *reinterpret_cast<const bf16x8*>(
        &Qh[(size_t)(q0w + l31) * 64 + dc * 16 + hi * 8]);

  f32x16 oacc[2];
#pragma unroll
  for (int db = 0; db < 2; ++db)
#pragma unroll
    for (int r = 0; r < 16; ++r) oacc[db][r] = 0.f;
  float dn = 0.f;

  // reg staging: 512 threads, 512 16B units per tile -> exactly 1 K unit + 1 V unit/thread
  bf16x8 kreg, vreg;
  int sr = t >> 3, sc = t & 7;
  auto stage_load = [&](int kt) {
    kreg = *reinterpret_cast<const bf16x8*>(&Kh[(size_t)(kt * 64 + sr) * 64 + sc * 8]);
    vreg = *reinterpret_cast<const bf16x8*>(&Vh[(size_t)sr * SEQ + kt * 64 + sc * 8]);
  };
  auto stage_write = [&](int buf) {
    *reinterpret_cast<bf16x8*>(&lK[buf][(sc * 65 + sr) * 8]) = kreg;
    *reinterpret_cast<bf16x8*>(&lV[buf][(sc * 65 + sr) * 8]) = vreg;
  };

  union PF { u32 w[4]; bf16x8 v; };
  int cur = 0;
  stage_load(0);
  stage_write(0);
  __syncthreads();
  for (int kt = 0; kt < SEQ / 64; ++kt) {
    if (kt + 1 < SEQ / 64) stage_load(kt + 1);  // in flight across compute (T14)

    f32x16 s[2];
#pragma unroll
    for (int cb = 0; cb < 2; ++cb)
#pragma unroll
      for (int r = 0; r < 16; ++r) s[cb][r] = 0.f;
    __builtin_amdgcn_s_setprio(1);
#pragma unroll
    for (int cb = 0; cb < 2; ++cb) {
#pragma unroll
      for (int dc = 0; dc < 4; ++dc) {
        bf16x8 kf = *reinterpret_cast<const bf16x8*>(
            &lK[cur][((dc * 2 + hi) * 65 + cb * 32 + l31) * 8]);
        s[cb] = __builtin_amdgcn_mfma_f32_32x32x16_bf16(kf, qf[dc], s[cb], 0, 0, 0);
      }
    }
    __builtin_amdgcn_s_setprio(0);

    PF pa[2][2];
#pragma unroll
    for (int cb = 0; cb < 2; ++cb) {
#pragma unroll
      for (int r = 0; r < 16; ++r) {
        float e = __builtin_amdgcn_exp2f(s[cb][r]);
        s[cb][r] = e;
        dn += e;
      }
#pragma unroll
      for (int c = 0; c < 2; ++c) {
        u32 u0 = f2u(s[cb][8 * c + 0]) + 0x8000u;
        u32 u1 = f2u(s[cb][8 * c + 1]) + 0x8000u;
        u32 u2 = f2u(s[cb][8 * c + 2]) + 0x8000u;
        u32 u3 = f2u(s[cb][8 * c + 3]) + 0x8000u;
        u32 u4 = f2u(s[cb][8 * c + 4]) + 0x8000u;
        u32 u5 = f2u(s[cb][8 * c + 5]) + 0x8000u;
        u32 u6 = f2u(s[cb][8 * c + 6]) + 0x8000u;
        u32 u7 = f2u(s[cb][8 * c + 7]) + 0x8000u;
        u32 a1 = __builtin_amdgcn_perm(u1, u0, 0x07060302);  // bf16(e1)<<16 | bf16(e0)
        u32 a2 = __builtin_amdgcn_perm(u3, u2, 0x07060302);
        u32 b1 = __builtin_amdgcn_perm(u5, u4, 0x07060302);
        u32 b2 = __builtin_amdgcn_perm(u7, u6, 0x07060302);
        asm("v_permlane32_swap_b32 %0, %1" : "+v"(a1), "+v"(b1));
        asm("v_permlane32_swap_b32 %0, %1" : "+v"(a2), "+v"(b2));
        pa[cb][c].w[0] = a1; pa[cb][c].w[1] = a2;
        pa[cb][c].w[2] = b1; pa[cb][c].w[3] = b2;
      }
    }

    __builtin_amdgcn_s_setprio(1);
#pragma unroll
    for (int cb = 0; cb < 2; ++cb)
#pragma unroll
      for (int c = 0; c < 2; ++c)
#pragma unroll
        for (int db = 0; db < 2; ++db) {
          bf16x8 vf = *reinterpret_cast<const bf16x8*>(
              &lV[cur][((cb * 4 + c * 2 + hi) * 65 + db * 32 + l31) * 8]);
          oacc[db] = __builtin_amdgcn_mfma_f32_32x32x16_bf16(pa[cb][c].v, vf, oacc[db], 0, 0, 0);
        }
    __builtin_amdgcn_s_setprio(0);

    if (kt + 1 < SEQ / 64) stage_write(cur ^ 1);  // implicit vmcnt wait lands here
    __syncthreads();
    cur ^= 1;
  }

  dn += __shfl_xor(dn, 32);
#pragma unroll
  for (int r = 0; r < 16; ++r) {
    int qrel = (r & 3) + 8 * (r >> 2) + 4 * hi;
    float dfull = __shfl(dn, qrel);
    float inv = __builtin_amdgcn_rcpf(dfull);
    int q = q0w + qrel;
#pragma unroll
    for (int db = 0; db < 2; ++db) {
      int d = db * 32 + l31;
      Out[(size_t)(b * SEQ + q) * EMB + h * 64 + d] = f2bf(oacc[db][r] * inv);
    }
  }
}

// ---------------- launch ----------------
extern "C" void kernel_launch(void* const* d_in, const int* in_sizes, int n_in,
                              void* d_out, int out_size, void* d_ws, size_t ws_size,
                              hipStream_t stream) {
  const float* x = (const float*)d_in[0];
  const float* bqkv = (const float*)d_in[2];
  const float* bout = (const float*)d_in[4];
  float* out = (float*)d_out;

  char* ws = (char*)d_ws;
  size_t off = 0;
  auto alloc = [&](size_t bytes) {
    void* p = ws + off;
    off += (bytes + 255) & ~(size_t)255;
    return p;
  };
  u16* xb    = (u16*)alloc((size_t)MTOT * EMB * 2);
  u16* wqkvb = (u16*)alloc((size_t)3 * EMB * EMB * 2);
  u16* woutb = (u16*)alloc((size_t)EMB * EMB * 2);
  u16* Qb    = (u16*)alloc((size_t)64 * SEQ * HD * 2);
  u16* Kb    = (u16*)alloc((size_t)64 * SEQ * HD * 2);
  u16* Vtb   = (u16*)alloc((size_t)64 * HD * SEQ * 2);
  u16* aout  = (u16*)alloc((size_t)MTOT * EMB * 2);
  float* tab2 = (float*)alloc((size_t)SEQ * 32 * 2 * 4);
  (void)ws_size; (void)in_sizes; (void)n_in; (void)out_size;

  prep_kernel<<<4096, 256, 0, stream>>>(x, (const float*)d_in[1], (const float*)d_in[3],
                                        xb, wqkvb, woutb, tab2);
  gemm_qkv_rope<<<64 * 24, 256, 0, stream>>>(xb, wqkvb, bqkv, tab2, Qb, Kb, Vtb);
  attn_kernel<<<64 * 8, 512, 0, stream>>>(Qb, Kb, Vtb, aout);
  gemm_bt_f32<<<64 * 8, 256, 0, stream>>>(aout, woutb, bout, out, EMB, 8);
}

// Round 16
// 169.576 us; speedup vs baseline: 1.1898x; 1.0024x over previous
//
#include <hip/hip_runtime.h>
#include <hip/hip_bf16.h>
#include <cstdint>
#include <cstddef>

#define SEQ 2048
#define NBATCH 4
#define EMB 1024
#define NH 16
#define HD 64
#define MTOT (NBATCH * SEQ)   // 8192

typedef __attribute__((ext_vector_type(8))) short bf16x8;
typedef __attribute__((ext_vector_type(4))) float f32x4;
typedef __attribute__((ext_vector_type(16))) float f32x16;
typedef unsigned short u16;
typedef unsigned int u32;

__device__ __forceinline__ float bf2f(u16 v) {
  union { u32 u; float f; } c; c.u = ((u32)v) << 16; return c.f;
}
__device__ __forceinline__ u16 f2bf(float f) {
  union { float f; u32 u; } c; c.f = f;
  u32 u = c.u;
  return (u16)((u + 0x7FFFu + ((u >> 16) & 1u)) >> 16);
}
__device__ __forceinline__ u32 f2u(float f) {
  union { float f; u32 u; } c; c.f = f; return c.u;
}

// ---------------- fused prep: casts (x, W_qkv, W_out) + RoPE table ----------------
__global__ void prep_kernel(const float* __restrict__ x, const float* __restrict__ wqkv,
                            const float* __restrict__ wout,
                            u16* __restrict__ xb, u16* __restrict__ wqkvb,
                            u16* __restrict__ woutb, float* __restrict__ tab2) {
  int tid = blockIdx.x * blockDim.x + threadIdx.x;
  int stride = gridDim.x * blockDim.x;
  for (int i = tid; i < MTOT * EMB / 4; i += stride) {
    float4 v = reinterpret_cast<const float4*>(x)[i];
    ushort4 o;
    o.x = f2bf(v.x); o.y = f2bf(v.y); o.z = f2bf(v.z); o.w = f2bf(v.w);
    reinterpret_cast<ushort4*>(xb)[i] = o;
  }
  for (int i = tid; i < 3 * EMB * EMB / 4; i += stride) {
    float4 v = reinterpret_cast<const float4*>(wqkv)[i];
    ushort4 o;
    o.x = f2bf(v.x); o.y = f2bf(v.y); o.z = f2bf(v.z); o.w = f2bf(v.w);
    reinterpret_cast<ushort4*>(wqkvb)[i] = o;
  }
  for (int i = tid; i < EMB * EMB / 4; i += stride) {
    float4 v = reinterpret_cast<const float4*>(wout)[i];
    ushort4 o;
    o.x = f2bf(v.x); o.y = f2bf(v.y); o.z = f2bf(v.z); o.w = f2bf(v.w);
    reinterpret_cast<ushort4*>(woutb)[i] = o;
  }
  for (int i = tid; i < SEQ * 32; i += stride) {
    int n = i >> 5, j = i & 31;
    float invf = 1.0f / powf(10000.0f, (float)(2 * j) / 64.0f);
    float ang = (float)n * invf;
    tab2[2 * i] = cosf(ang);
    tab2[2 * i + 1] = sinf(ang);
  }
}

// ---------------- async global->LDS helper (16B) ----------------
__device__ __forceinline__ void gld_lds16(const u16* g, u16* l) {
  __builtin_amdgcn_global_load_lds((const __attribute__((address_space(1))) void*)g,
                                   (__attribute__((address_space(3))) void*)l, 16, 0, 0);
}

// ---------------- GEMM: C[M,N] = A[M,K] * Bw[N,K]^T + bias (out-proj, fp32 out) ----------------
// XCD-locality swizzle: bm%8 == XCD -> each A row-tile is fetched by exactly one XCD's L2.
__global__ __launch_bounds__(256, 2)
void gemm_bt_f32(const u16* __restrict__ A, const u16* __restrict__ Bw,
                 const float* __restrict__ bias, float* __restrict__ Cout,
                 int N, int tiles_n) {
  __shared__ u16 lA[128 * 64];
  __shared__ u16 lB[128 * 64];
  const int K = 1024;
  int g = blockIdx.x;
  int xcd = g & 7, idx = g >> 3;
  int bm = (idx & 7) * 8 + xcd;     // bm%8 == xcd (64 bm values per 8 XCDs)
  int bn = idx >> 3;                // 0..tiles_n-1
  int t = threadIdx.x;
  int wave = t >> 6, lane = t & 63;
  int wm = wave >> 1, wn = wave & 1;
  int l15 = lane & 15, l4 = lane >> 4;

  f32x4 acc[4][4];
#pragma unroll
  for (int i = 0; i < 4; ++i)
#pragma unroll
    for (int j = 0; j < 4; ++j) acc[i][j] = (f32x4){0.f, 0.f, 0.f, 0.f};

  int su[4], sr[4], sc[4];
#pragma unroll
  for (int i = 0; i < 4; ++i) {
    int u = (i * 4 + wave) * 64 + lane;
    su[i] = u;
    sr[i] = u >> 3;
    sc[i] = (u & 7) ^ (sr[i] & 7);
  }

  for (int kt = 0; kt < K / 64; ++kt) {
    if (kt) __syncthreads();
#pragma unroll
    for (int i = 0; i < 4; ++i) {
      gld_lds16(A + (size_t)(bm * 128 + sr[i]) * K + kt * 64 + sc[i] * 8, &lA[su[i] * 8]);
      gld_lds16(Bw + (size_t)(bn * 128 + sr[i]) * K + kt * 64 + sc[i] * 8, &lB[su[i] * 8]);
    }
    __syncthreads();
#pragma unroll
    for (int ks = 0; ks < 2; ++ks) {
      bf16x8 af[4], bfr[4];
#pragma unroll
      for (int mb = 0; mb < 4; ++mb) {
        int r = wm * 64 + mb * 16 + l15;
        int cc = (ks * 4 + l4) ^ (r & 7);
        af[mb] = *reinterpret_cast<const bf16x8*>(&lA[r * 64 + cc * 8]);
      }
#pragma unroll
      for (int nb = 0; nb < 4; ++nb) {
        int r = wn * 64 + nb * 16 + l15;
        int cc = (ks * 4 + l4) ^ (r & 7);
        bfr[nb] = *reinterpret_cast<const bf16x8*>(&lB[r * 64 + cc * 8]);
      }
#pragma unroll
      for (int mb = 0; mb < 4; ++mb)
#pragma unroll
        for (int nb = 0; nb < 4; ++nb)
          acc[mb][nb] = __builtin_amdgcn_mfma_f32_16x16x32_bf16(af[mb], bfr[nb], acc[mb][nb], 0, 0, 0);
    }
  }

#pragma unroll
  for (int mb = 0; mb < 4; ++mb)
#pragma unroll
    for (int nb = 0; nb < 4; ++nb) {
      int row0 = bm * 128 + wm * 64 + mb * 16 + l4 * 4;
      int col = bn * 128 + wn * 64 + nb * 16 + l15;
      float bv = bias[col];
#pragma unroll
      for (int r = 0; r < 4; ++r)
        Cout[(size_t)(row0 + r) * N + col] = acc[mb][nb][r] + bv;
    }
}

// ---------------- fused QKV GEMM + bias + RoPE + scatter (coalesced Q/K stores) ----------------
__global__ __launch_bounds__(256, 2)
void gemm_qkv_rope(const u16* __restrict__ A, const u16* __restrict__ Bw,
                   const float* __restrict__ bias, const float* __restrict__ tab2,
                   u16* __restrict__ Qb, u16* __restrict__ Kb, u16* __restrict__ Vtb) {
  __shared__ u16 lA[128 * 64];
  __shared__ u16 lB[128 * 64];
  const int K = 1024;
  int g = blockIdx.x;
  int xcd = g & 7, idx = g >> 3;
  int bm = (idx & 7) * 8 + xcd;     // 0..63 ; bm%8 == xcd
  int bn = idx >> 3;                // 0..23
  int t = threadIdx.x;
  int wave = t >> 6, lane = t & 63;
  int wm = wave >> 1, wn = wave & 1;
  int l15 = lane & 15, l4 = lane >> 4;

  f32x4 acc[4][4];
#pragma unroll
  for (int i = 0; i < 4; ++i)
#pragma unroll
    for (int j = 0; j < 4; ++j) acc[i][j] = (f32x4){0.f, 0.f, 0.f, 0.f};

  int su[4], sr[4], sc[4];
#pragma unroll
  for (int i = 0; i < 4; ++i) {
    int u = (i * 4 + wave) * 64 + lane;
    su[i] = u;
    sr[i] = u >> 3;
    sc[i] = (u & 7) ^ (sr[i] & 7);
  }
  // B row permutation: within each 64-row half, LDS row rr holds weight row tau(rr)
  int tauB[4];
#pragma unroll
  for (int i = 0; i < 4; ++i) {
    int rr = sr[i] & 63;
    tauB[i] = (sr[i] & 64) | (rr & 32) | ((rr & 15) << 1) | ((rr >> 4) & 1);
  }

  for (int kt = 0; kt < K / 64; ++kt) {
    if (kt) __syncthreads();
#pragma unroll
    for (int i = 0; i < 4; ++i) {
      gld_lds16(A + (size_t)(bm * 128 + sr[i]) * K + kt * 64 + sc[i] * 8, &lA[su[i] * 8]);
      gld_lds16(Bw + (size_t)(bn * 128 + tauB[i]) * K + kt * 64 + sc[i] * 8, &lB[su[i] * 8]);
    }
    __syncthreads();
#pragma unroll
    for (int ks = 0; ks < 2; ++ks) {
      bf16x8 af[4], bfr[4];
#pragma unroll
      for (int mb = 0; mb < 4; ++mb) {
        int r = wm * 64 + mb * 16 + l15;
        int cc = (ks * 4 + l4) ^ (r & 7);
        af[mb] = *reinterpret_cast<const bf16x8*>(&lA[r * 64 + cc * 8]);
      }
#pragma unroll
      for (int nb = 0; nb < 4; ++nb) {
        int r = wn * 64 + nb * 16 + l15;
        int cc = (ks * 4 + l4) ^ (r & 7);
        bfr[nb] = *reinterpret_cast<const bf16x8*>(&lB[r * 64 + cc * 8]);
      }
#pragma unroll
      for (int mb = 0; mb < 4; ++mb)
#pragma unroll
        for (int nb = 0; nb < 4; ++nb)
          acc[mb][nb] = __builtin_amdgcn_mfma_f32_16x16x32_bf16(af[mb], bfr[nb], acc[mb][nb], 0, 0, 0);
    }
  }

  // ---- fused epilogue ----
  int type = bn >> 3;            // 0=q, 1=k, 2=v
  int h = (bn * 2 + wn) & 15;    // head
  int colbase = bn * 128 + wn * 64;
  float bv[4];
#pragma unroll
  for (int nb = 0; nb < 4; ++nb)
    bv[nb] = bias[colbase + 32 * (nb >> 1) + 2 * l15 + (nb & 1)];

  if (type < 2) {
    u16* dst0 = (type == 0) ? Qb : Kb;
    float qs = (type == 0) ? 0.1803368801111163f : 1.0f;  // (1/8)*log2(e) folded into q
#pragma unroll
    for (int mb = 0; mb < 4; ++mb) {
      int row0 = bm * 128 + wm * 64 + mb * 16 + l4 * 4;
#pragma unroll
      for (int r = 0; r < 4; ++r) {
        int row = row0 + r;
        int bb = row >> 11, nl = row & 2047;
        float4 cs4 = *reinterpret_cast<const float4*>(tab2 + (size_t)nl * 64 + 4 * l15);
        float a0 = acc[mb][0][r] + bv[0];   // d = 2l15
        float a1 = acc[mb][1][r] + bv[1];   // d = 2l15+1
        float a2 = acc[mb][2][r] + bv[2];   // d = 2l15+32
        float a3 = acc[mb][3][r] + bv[3];   // d = 2l15+33
        float o0 = (a0 * cs4.x - a2 * cs4.y) * qs;
        float o2 = (a2 * cs4.x + a0 * cs4.y) * qs;
        float o1 = (a1 * cs4.z - a3 * cs4.w) * qs;
        float o3 = (a3 * cs4.z + a1 * cs4.w) * qs;
        u16* dst = dst0 + ((size_t)(bb * 16 + h) * SEQ + nl) * 64;
        u32 lo = (u32)f2bf(o0) | ((u32)f2bf(o1) << 16);
        u32 hi2 = (u32)f2bf(o2) | ((u32)f2bf(o3) << 16);
        *reinterpret_cast<u32*>(&dst[2 * l15]) = lo;
        *reinterpret_cast<u32*>(&dst[32 + 2 * l15]) = hi2;
      }
    }
  } else {
#pragma unroll
    for (int mb = 0; mb < 4; ++mb) {
      int row0 = bm * 128 + wm * 64 + mb * 16 + l4 * 4;
      int bb = row0 >> 11, nl0 = row0 & 2047;
#pragma unroll
      for (int nb = 0; nb < 4; ++nb) {
        int d = 32 * (nb >> 1) + 2 * l15 + (nb & 1);
        ushort4 pk;
        pk.x = f2bf(acc[mb][nb][0] + bv[nb]);
        pk.y = f2bf(acc[mb][nb][1] + bv[nb]);
        pk.z = f2bf(acc[mb][nb][2] + bv[nb]);
        pk.w = f2bf(acc[mb][nb][3] + bv[nb]);
        *reinterpret_cast<ushort4*>(&Vtb[((size_t)(bb * 16 + h) * 64 + d) * SEQ + nl0]) = pk;
      }
    }
  }
}

// ---------------- attention v13: v12 + zacc seeding + MFMA-pipe denominator (ones-trick) ----------------
// 512 threads = 8 waves, 32 q-rows/wave, 2 blocks/CU (16 waves/CU). Conflict-free padded
// chunk-major LDS; T14 reg-staging. VALU slimmed: no S zero-init (zacc C-operand), no dn
// adds (dacc = mfma(pa, ones) on the matrix pipe; round-10-proven numerics with RHU pack),
// epilogue shuffle-free (dacc layout aligns with oacc).
__global__ __launch_bounds__(512, 4)
void attn_kernel(const u16* __restrict__ Q, const u16* __restrict__ Kk,
                 const u16* __restrict__ Vt, u16* __restrict__ Out) {
  int bid = blockIdx.x;
  int swz = (bid & 7) * 64 + (bid >> 3);  // 512 = 8 XCD x 64 ; each XCD owns 8 heads
  int bh = swz >> 3;
  int qt = swz & 7;
  int b = bh >> 4, h = bh & 15;
  int t = threadIdx.x;
  int wave = t >> 6, lane = t & 63;
  int l31 = lane & 31, hi = lane >> 5;

  __shared__ u16 lK[2][520 * 8];  // 8 chunks * 65 (64 rows + 1 pad) 16B slots
  __shared__ u16 lV[2][520 * 8];

  const u16* Qh = Q + (size_t)bh * SEQ * 64;
  const u16* Kh = Kk + (size_t)bh * SEQ * 64;
  const u16* Vh = Vt + (size_t)bh * 64 * SEQ;
  int q0w = qt * 256 + wave * 32;

  bf16x8 qf[4];
#pragma unroll
  for (int dc = 0; dc < 4; ++dc)
    qf[dc] = *reinterpret_cast<const bf16x8*>(
        &Qh[(size_t)(q0w + l31) * 64 + dc * 16 + hi * 8]);

  f32x16 oacc[2];
#pragma unroll
  for (int db = 0; db < 2; ++db)
#pragma unroll
    for (int r = 0; r < 16; ++r) oacc[db][r] = 0.f;
  f32x16 dacc;
#pragma unroll
  for (int r = 0; r < 16; ++r) dacc[r] = 0.f;
  f32x16 zacc;  // loop-invariant zeros: C-operand for each QK chain's first MFMA
#pragma unroll
  for (int r = 0; r < 16; ++r) zacc[r] = 0.f;
  bf16x8 ones;  // bf16 1.0 broadcast (B-operand of denom MFMA)
#pragma unroll
  for (int j = 0; j < 8; ++j) ones[j] = (short)0x3F80;

  // reg staging: 512 threads, 512 16B units per tile -> exactly 1 K unit + 1 V unit/thread
  bf16x8 kreg, vreg;
  int sr = t >> 3, sc = t & 7;
  auto stage_load = [&](int kt) {
    kreg = *reinterpret_cast<const bf16x8*>(&Kh[(size_t)(kt * 64 + sr) * 64 + sc * 8]);
    vreg = *reinterpret_cast<const bf16x8*>(&Vh[(size_t)sr * SEQ + kt * 64 + sc * 8]);
  };
  auto stage_write = [&](int buf) {
    *reinterpret_cast<bf16x8*>(&lK[buf][(sc * 65 + sr) * 8]) = kreg;
    *reinterpret_cast<bf16x8*>(&lV[buf][(sc * 65 + sr) * 8]) = vreg;
  };

  union PF { u32 w[4]; bf16x8 v; };
  int cur = 0;
  stage_load(0);
  stage_write(0);
  __syncthreads();
  for (int kt = 0; kt < SEQ / 64; ++kt) {
    if (kt + 1 < SEQ / 64) stage_load(kt + 1);  // in flight across compute (T14)

    // ---- QK^T swapped: S^T[k][q] ; zacc-seeded first MFMA (no per-iter S zero-init)
    f32x16 s[2];
    __builtin_amdgcn_s_setprio(1);
#pragma unroll
    for (int cb = 0; cb < 2; ++cb) {
#pragma unroll
      for (int dc = 0; dc < 4; ++dc) {
        bf16x8 kf = *reinterpret_cast<const bf16x8*>(
            &lK[cur][((dc * 2 + hi) * 65 + cb * 32 + l31) * 8]);
        s[cb] = __builtin_amdgcn_mfma_f32_32x32x16_bf16(kf, qf[dc], dc ? s[cb] : zacc, 0, 0, 0);
      }
    }
    __builtin_amdgcn_s_setprio(0);

    // ---- softmax in-register: exp2, RHU + v_perm pack (denominator NOT summed on VALU)
    PF pa[2][2];
#pragma unroll
    for (int cb = 0; cb < 2; ++cb) {
#pragma unroll
      for (int r = 0; r < 16; ++r) s[cb][r] = __builtin_amdgcn_exp2f(s[cb][r]);
#pragma unroll
      for (int c = 0; c < 2; ++c) {
        u32 u0 = f2u(s[cb][8 * c + 0]) + 0x8000u;
        u32 u1 = f2u(s[cb][8 * c + 1]) + 0x8000u;
        u32 u2 = f2u(s[cb][8 * c + 2]) + 0x8000u;
        u32 u3 = f2u(s[cb][8 * c + 3]) + 0x8000u;
        u32 u4 = f2u(s[cb][8 * c + 4]) + 0x8000u;
        u32 u5 = f2u(s[cb][8 * c + 5]) + 0x8000u;
        u32 u6 = f2u(s[cb][8 * c + 6]) + 0x8000u;
        u32 u7 = f2u(s[cb][8 * c + 7]) + 0x8000u;
        u32 a1 = __builtin_amdgcn_perm(u1, u0, 0x07060302);  // bf16(e1)<<16 | bf16(e0)
        u32 a2 = __builtin_amdgcn_perm(u3, u2, 0x07060302);
        u32 b1 = __builtin_amdgcn_perm(u5, u4, 0x07060302);
        u32 b2 = __builtin_amdgcn_perm(u7, u6, 0x07060302);
        asm("v_permlane32_swap_b32 %0, %1" : "+v"(a1), "+v"(b1));
        asm("v_permlane32_swap_b32 %0, %1" : "+v"(a2), "+v"(b2));
        pa[cb][c].w[0] = a1; pa[cb][c].w[1] = a2;
        pa[cb][c].w[2] = b1; pa[cb][c].w[3] = b2;
      }
    }

    // ---- PV + denom: O[q][d] and dacc[q] = sum_k P (ones-B MFMA, aligned with oacc layout)
    __builtin_amdgcn_s_setprio(1);
#pragma unroll
    for (int cb = 0; cb < 2; ++cb)
#pragma unroll
      for (int c = 0; c < 2; ++c) {
#pragma unroll
        for (int db = 0; db < 2; ++db) {
          bf16x8 vf = *reinterpret_cast<const bf16x8*>(
              &lV[cur][((cb * 4 + c * 2 + hi) * 65 + db * 32 + l31) * 8]);
          oacc[db] = __builtin_amdgcn_mfma_f32_32x32x16_bf16(pa[cb][c].v, vf, oacc[db], 0, 0, 0);
        }
        dacc = __builtin_amdgcn_mfma_f32_32x32x16_bf16(pa[cb][c].v, ones, dacc, 0, 0, 0);
      }
    __builtin_amdgcn_s_setprio(0);

    if (kt + 1 < SEQ / 64) stage_write(cur ^ 1);  // implicit vmcnt wait lands here
    __syncthreads();
    cur ^= 1;
  }

  // ---- epilogue: dacc[r] = denom for q = crow(r,hi) — shuffle-free
#pragma unroll
  for (int r = 0; r < 16; ++r) {
    int qrel = (r & 3) + 8 * (r >> 2) + 4 * hi;
    float inv = __builtin_amdgcn_rcpf(dacc[r]);
    int q = q0w + qrel;
#pragma unroll
    for (int db = 0; db < 2; ++db) {
      int d = db * 32 + l31;
      Out[(size_t)(b * SEQ + q) * EMB + h * 64 + d] = f2bf(oacc[db][r] * inv);
    }
  }
}

// ---------------- launch ----------------
extern "C" void kernel_launch(void* const* d_in, const int* in_sizes, int n_in,
                              void* d_out, int out_size, void* d_ws, size_t ws_size,
                              hipStream_t stream) {
  const float* x = (const float*)d_in[0];
  const float* bqkv = (const float*)d_in[2];
  const float* bout = (const float*)d_in[4];
  float* out = (float*)d_out;

  char* ws = (char*)d_ws;
  size_t off = 0;
  auto alloc = [&](size_t bytes) {
    void* p = ws + off;
    off += (bytes + 255) & ~(size_t)255;
    return p;
  };
  u16* xb    = (u16*)alloc((size_t)MTOT * EMB * 2);
  u16* wqkvb = (u16*)alloc((size_t)3 * EMB * EMB * 2);
  u16* woutb = (u16*)alloc((size_t)EMB * EMB * 2);
  u16* Qb    = (u16*)alloc((size_t)64 * SEQ * HD * 2);
  u16* Kb    = (u16*)alloc((size_t)64 * SEQ * HD * 2);
  u16* Vtb   = (u16*)alloc((size_t)64 * HD * SEQ * 2);
  u16* aout  = (u16*)alloc((size_t)MTOT * EMB * 2);
  float* tab2 = (float*)alloc((size_t)SEQ * 32 * 2 * 4);
  (void)ws_size; (void)in_sizes; (void)n_in; (void)out_size;

  prep_kernel<<<4096, 256, 0, stream>>>(x, (const float*)d_in[1], (const float*)d_in[3],
                                        xb, wqkvb, woutb, tab2);
  gemm_qkv_rope<<<64 * 24, 256, 0, stream>>>(xb, wqkvb, bqkv, tab2, Qb, Kb, Vtb);
  attn_kernel<<<64 * 8, 512, 0, stream>>>(Qb, Kb, Vtb, aout);
  gemm_bt_f32<<<64 * 8, 256, 0, stream>>>(aout, woutb, bout, out, EMB, 8);
}